// Round 1
// baseline (1286.845 us; speedup 1.0000x reference)
//
#include <hip/hip_runtime.h>
#include <hip/hip_bf16.h>

#define EPSR 1e-8f
#define BNEPS 1e-3f
#define LOG2PI 1.8378770664093453f

// ---------------- ws layout (float offsets) ----------------
#define O_H      0          // h:     2*64*64*96   = 786432
#define O_POSE2  786432     // pose2: 2*28*28*512  = 802816
#define O_ACT2   1589248    // act2:  2*28*28*32   = 50176
#define O_POSE3  1639424    // pose3: 2*13*13*512  = 173056
#define O_ACT3   1812480    // act3:  2*13*13*32   = 10816
#define O_POSE4  1823296    // pose4: 2*6*6*512    = 36864
#define O_ACT4   1860160    // act4:  2*6*6*32     = 2304
#define O_DECIN  1862464    // 2*512
#define O_H1     1863488    // 2*512
#define O_H2     1864512    // 2*1024
#define O_PART   1866560    // max 8*2*8192 = 131072
// total 1997632 floats ~= 8 MB

// ---------------- conv1: 11x11 s2 SAME 3->96 + bias + relu + BN1 ----------------
__global__ __launch_bounds__(256) void conv1_k(
    const float* __restrict__ x, const float* __restrict__ w,
    const float* __restrict__ bias, const float* __restrict__ bn1,
    float* __restrict__ h)
{
  int t = blockIdx.x * 256 + threadIdx.x;        // 786432 total
  int c = t % 96; int px = t / 96;
  int ox = px & 63; int r = px >> 6; int oy = r & 63; int b = r >> 6;
  float acc = 0.f;
  int iy0 = 2*oy - 4, ix0 = 2*ox - 4;
  for (int ky = 0; ky < 11; ++ky) {
    int iy = iy0 + ky;
    if ((unsigned)iy > 127u) continue;
    const float* xrow = x + (size_t)((b*128 + iy)*128)*3;
    const float* wrow = w + (ky*11*3)*96 + c;
    for (int kx = 0; kx < 11; ++kx) {
      int ix = ix0 + kx;
      if ((unsigned)ix > 127u) continue;
      const float* xp = xrow + ix*3;
      const float* wp = wrow + kx*3*96;
      acc = fmaf(xp[0], wp[0],   acc);
      acc = fmaf(xp[1], wp[96],  acc);
      acc = fmaf(xp[2], wp[192], acc);
    }
  }
  acc += bias[c];
  acc = fmaxf(acc, 0.f);
  float g = bn1[c], be = bn1[96+c], mm = bn1[192+c], vv = bn1[288+c];
  h[t] = (acc - mm) * (g * rsqrtf(vv + BNEPS)) + be;
}

// ---------------- primary caps conv as implicit GEMM ----------------
// A: im2col of h -> [1568][7776], B: weights [7776][512 pose | 32 act]
// block: 256 thr, tile BM=64 x BN=64, BK=16, thread tile 4x4, double-buffered LDS
__global__ __launch_bounds__(256) void conv2_gemm(
    const float* __restrict__ h,
    const float* __restrict__ pw, const float* __restrict__ pb,
    const float* __restrict__ aw, const float* __restrict__ ab,
    const float* __restrict__ bn2,
    float* __restrict__ pose2, float* __restrict__ act2)
{
  __shared__ float As[2][16][68];
  __shared__ float Bs[2][16][68];
  const int tid = threadIdx.x;
  const int mb = blockIdx.x, nb = blockIdx.y;
  const int m0 = mb * 64;
  const float* Bp; int ldB, n0;
  if (nb < 8) { Bp = pw; ldB = 512; n0 = nb * 64; } else { Bp = aw; ldB = 32; n0 = 0; }

  // A staging: thread loads one float4 of ci for one m
  const int a_ml = tid & 63, a_cig = tid >> 6;
  const int am = m0 + a_ml;
  const bool am_ok = am < 1568;
  int ab_ = am / 784; int ayx = am - ab_*784;
  int aoy = ayx / 28, aox = ayx - aoy*28;
  if (!am_ok) { ab_ = 0; aoy = 0; aox = 0; }
  const float* a_base = h + (size_t)((ab_*64 + 2*aoy)*64 + 2*aox)*96 + a_cig*4;

  // B staging
  const int b_kk = tid >> 4, b_ng = tid & 15;
  const int b_col = b_ng * 4;
  const bool b_ok = b_col < ldB;

  // compute mapping: 16 m-groups x 16 n-groups
  const int tm = (tid & 15) * 4, tn = (tid >> 4) * 4;

  float acc[4][4] = {{0}};

  auto ldAv = [&](int ky, int kx, int ci0) -> float4 {
    if (!am_ok) return make_float4(0,0,0,0);
    return *(const float4*)(a_base + (ky*64 + kx)*96 + ci0);
  };
  auto ldBv = [&](const float* p) -> float4 {
    if (!b_ok) return make_float4(0,0,0,0);
    return *(const float4*)p;
  };
  auto wrAv = [&](float4 v, int buf) {
    As[buf][a_cig*4+0][a_ml] = v.x;
    As[buf][a_cig*4+1][a_ml] = v.y;
    As[buf][a_cig*4+2][a_ml] = v.z;
    As[buf][a_cig*4+3][a_ml] = v.w;
  };
  auto wrBv = [&](float4 v, int buf) {
    *(float4*)&Bs[buf][b_kk][b_col] = v;
  };

  const float* bp = Bp + (size_t)b_kk * ldB + n0 + b_col;
  // prologue
  {
    float4 va = ldAv(0,0,0);
    float4 vb = ldBv(bp);
    wrAv(va, 0); wrBv(vb, 0);
  }
  __syncthreads();

  int ky = 0, kx = 0, ci0 = 0;
  const float* bnext = bp;
  for (int kt = 0; kt < 486; ++kt) {
    int cur = kt & 1;
    float4 va, vb;
    bool do_stage = (kt < 485);
    if (do_stage) {
      ci0 += 16;
      if (ci0 == 96) { ci0 = 0; if (++kx == 9) { kx = 0; ++ky; } }
      bnext += 16 * ldB;
      va = ldAv(ky, kx, ci0);      // issue loads early; hide under FMA block
      vb = ldBv(bnext);
    }
    #pragma unroll
    for (int kk = 0; kk < 16; ++kk) {
      float4 av = *(const float4*)&As[cur][kk][tm];
      float4 bv = *(const float4*)&Bs[cur][kk][tn];
      float aa[4] = {av.x, av.y, av.z, av.w};
      float bb4[4] = {bv.x, bv.y, bv.z, bv.w};
      #pragma unroll
      for (int i = 0; i < 4; ++i)
        #pragma unroll
        for (int j = 0; j < 4; ++j)
          acc[i][j] = fmaf(aa[i], bb4[j], acc[i][j]);
    }
    if (do_stage) { wrAv(va, cur ^ 1); wrBv(vb, cur ^ 1); }
    __syncthreads();
  }

  // epilogue: bias + (BN2 for pose | sigmoid for act)
  #pragma unroll
  for (int i = 0; i < 4; ++i) {
    int m = m0 + tm + i;
    if (m >= 1568) break;
    int b = m / 784; int yx = m - b*784; int oy = yx / 28, ox = yx - oy*28;
    int pix = (b*28 + oy)*28 + ox;
    #pragma unroll
    for (int j = 0; j < 4; ++j) {
      float val = acc[i][j];
      int nl = tn + j;
      if (nb < 8) {
        int n = n0 + nl;
        val += pb[n];
        int caps = n >> 4;
        float g = bn2[caps], be = bn2[32+caps], mm = bn2[64+caps], vv = bn2[96+caps];
        val = (val - mm) * (g * rsqrtf(vv + BNEPS)) + be;
        pose2[(size_t)pix*512 + n] = val;
      } else if (nl < 32) {
        val += ab[nl];
        act2[(size_t)pix*32 + nl] = 1.f / (1.f + expf(-val));
      }
    }
  }
}

// ---------------- fused votes + EM routing ----------------
// One block per output position (CONV) or per batch element (dense).
// lane = (o = lane&31, half = lane>>5 covering d = half*8..half*8+7)
// 3 passes; pass p uses R derived from pass p-1 stats (R never materialized).
template<int NIN, int NWAVES, bool CONV>
__global__ __launch_bounds__(NWAVES*64) void routing_k(
    const float* __restrict__ pose_in, const float* __restrict__ act_in,
    const float* __restrict__ Wv,
    const float* __restrict__ ba, const float* __restrict__ bu,
    const float* __restrict__ bn,
    float* __restrict__ pose_out, float* __restrict__ act_out,
    int Hin, int Win, int Wout)
{
  constexpr int NT  = NWAVES * 64;
  constexpr int NPW = NIN / NWAVES;
  __shared__ float s1s[NWAVES][32*17];
  __shared__ float s2s[NWAVES][32*17];
  __shared__ float rsP[NWAVES][32];
  __shared__ float muS[32*17], isgS[32*17], lgS[32*17];
  __shared__ float laS[32], lsS[32], aoS[32], RsS[32], S0S[32];

  const int tid = threadIdx.x;
  const int wv = tid >> 6, lane = tid & 63;
  const int o = lane & 31, half = lane >> 5;

  int bb = 0, oy = 0, ox = 0;
  if (CONV) {
    int px = blockIdx.x;
    ox = px % Wout; int t2 = px / Wout; oy = t2 % Wout; bb = t2 / Wout;
  } else {
    bb = blockIdx.x;
  }

  float mur[8], isgr[8], lar = 0.f, lsr = 0.f;
  #pragma unroll
  for (int i = 0; i < 8; ++i) { mur[i] = 0.f; isgr[i] = 0.f; }

  for (int p = 0; p < 3; ++p) {
    float lam = 0.01f * (float)(p + 1);
    float s1r[8] = {0,0,0,0,0,0,0,0};
    float s2r[8] = {0,0,0,0,0,0,0,0};
    float rsr = 0.f;

    for (int it = 0; it < NPW; ++it) {
      int n = wv * NPW + it;
      const float* wp = Wv + (size_t)(n*32 + o) * 16;
      float4 w0 = *(const float4*)(wp);
      float4 w1 = *(const float4*)(wp + 4);
      float4 w2 = *(const float4*)(wp + 8);
      float4 w3 = *(const float4*)(wp + 12);
      const float* pp; float an;
      if (CONV) {
        int c = n & 31, kk = n >> 5;
        int ki = kk / 3, kj = kk - ki*3;
        int pix = (bb*Hin + 2*oy + ki)*Win + 2*ox + kj;
        pp = pose_in + (size_t)(pix*32 + c) * 16;
        an = act_in[pix*32 + c];
      } else {
        pp = pose_in + (size_t)(bb*NIN + n) * 16;
        an = act_in[bb*NIN + n];
      }
      float4 p0 = *(const float4*)(pp + half*8);
      float4 p1 = *(const float4*)(pp + half*8 + 4);
      float v[8];
      v[0] = fmaf(p0.x,w0.x, fmaf(p0.y,w1.x, fmaf(p0.z,w2.x, p0.w*w3.x)));
      v[1] = fmaf(p0.x,w0.y, fmaf(p0.y,w1.y, fmaf(p0.z,w2.y, p0.w*w3.y)));
      v[2] = fmaf(p0.x,w0.z, fmaf(p0.y,w1.z, fmaf(p0.z,w2.z, p0.w*w3.z)));
      v[3] = fmaf(p0.x,w0.w, fmaf(p0.y,w1.w, fmaf(p0.z,w2.w, p0.w*w3.w)));
      v[4] = fmaf(p1.x,w0.x, fmaf(p1.y,w1.x, fmaf(p1.z,w2.x, p1.w*w3.x)));
      v[5] = fmaf(p1.x,w0.y, fmaf(p1.y,w1.y, fmaf(p1.z,w2.y, p1.w*w3.y)));
      v[6] = fmaf(p1.x,w0.z, fmaf(p1.y,w1.z, fmaf(p1.z,w2.z, p1.w*w3.z)));
      v[7] = fmaf(p1.x,w0.w, fmaf(p1.y,w1.w, fmaf(p1.z,w2.w, p1.w*w3.w)));

      float R;
      if (p == 0) {
        R = 1.f / 32.f;
      } else {
        float t = 0.f;
        #pragma unroll
        for (int dd = 0; dd < 8; ++dd) { float df = v[dd] - mur[dd]; t = fmaf(df*df, isgr[dd], t); }
        t += __shfl_xor(t, 32, 64);                   // full sum over 16 dims
        float logit = lar - 0.5f * (t + lsr);
        float mx = logit;
        mx = fmaxf(mx, __shfl_xor(mx, 16, 64));
        mx = fmaxf(mx, __shfl_xor(mx,  8, 64));
        mx = fmaxf(mx, __shfl_xor(mx,  4, 64));
        mx = fmaxf(mx, __shfl_xor(mx,  2, 64));
        mx = fmaxf(mx, __shfl_xor(mx,  1, 64));
        float e = expf(logit - mx);
        float se = e;
        se += __shfl_xor(se, 16, 64);
        se += __shfl_xor(se,  8, 64);
        se += __shfl_xor(se,  4, 64);
        se += __shfl_xor(se,  2, 64);
        se += __shfl_xor(se,  1, 64);
        R = e / se;
      }
      float Ra = R * an;
      rsr += Ra;
      #pragma unroll
      for (int dd = 0; dd < 8; ++dd) {
        s1r[dd] = fmaf(Ra, v[dd], s1r[dd]);
        s2r[dd] = fmaf(Ra * v[dd], v[dd], s2r[dd]);
      }
    }

    // cross-wave reduction
    #pragma unroll
    for (int dd = 0; dd < 8; ++dd) {
      s1s[wv][o*17 + half*8 + dd] = s1r[dd];
      s2s[wv][o*17 + half*8 + dd] = s2r[dd];
    }
    if (!half) rsP[wv][o] = rsr;
    __syncthreads();
    if (tid < 32) {
      float r = 0.f;
      #pragma unroll
      for (int w2 = 0; w2 < NWAVES; ++w2) r += rsP[w2][tid];
      S0S[tid] = r; RsS[tid] = r + EPSR;
    }
    __syncthreads();
    for (int idx = tid; idx < 512; idx += NT) {
      int oo = idx >> 4, d = idx & 15;
      float S1 = 0.f, S2 = 0.f;
      #pragma unroll
      for (int w2 = 0; w2 < NWAVES; ++w2) { S1 += s1s[w2][oo*17+d]; S2 += s2s[w2][oo*17+d]; }
      float Rs = RsS[oo];
      float m_ = S1 / Rs;
      float sg = (S2 - 2.f*m_*S1 + m_*m_*S0S[oo]) / Rs + EPSR;   // E[v^2]-mu^2 form
      muS[oo*17+d]  = m_;
      isgS[oo*17+d] = 1.f / sg;
      lgS[oo*17+d]  = logf(sg);
    }
    __syncthreads();
    if (tid < 32) {
      float L = 0.f;
      #pragma unroll
      for (int d = 0; d < 16; ++d) L += lgS[tid*17 + d];
      float cost = (16.f*bu[tid] + 0.5f*L) * RsS[tid];
      float av = 1.f / (1.f + expf(-lam * (ba[tid] - cost)));
      aoS[tid] = av;
      laS[tid] = logf(av + EPSR);
      lsS[tid] = 16.f*LOG2PI + L;
    }
    __syncthreads();
    if (p < 2) {
      #pragma unroll
      for (int dd = 0; dd < 8; ++dd) {
        mur[dd]  = muS[o*17 + half*8 + dd];
        isgr[dd] = isgS[o*17 + half*8 + dd];
      }
      lar = laS[o]; lsr = lsS[o];
    }
  }

  // outputs
  if (CONV) {
    int pxo = (bb*Wout + oy)*Wout + ox;
    for (int idx = tid; idx < 512; idx += NT) {
      int oo = idx >> 4, d = idx & 15;
      float val = muS[oo*17 + d];
      float g = bn[oo], be = bn[32+oo], mm = bn[64+oo], vv = bn[96+oo];
      val = (val - mm) * (g * rsqrtf(vv + BNEPS)) + be;
      pose_out[(size_t)pxo*512 + idx] = val;
    }
    if (tid < 32) act_out[(size_t)pxo*32 + tid] = aoS[tid];
  } else {
    for (int idx = tid; idx < 512; idx += NT)
      pose_out[(size_t)bb*512 + idx] = muS[(idx>>4)*17 + (idx&15)];
  }
}

// ---------------- decoder FC: K-split partial + reduce ----------------
__global__ __launch_bounds__(256) void fc_partial(
    const float* __restrict__ in, const float* __restrict__ W,
    float* __restrict__ part, int K, int N, int CK)
{
  int t = blockIdx.x * 256 + threadIdx.x;
  int nj = N >> 2;
  int j4 = t % nj, ks = t / nj;
  int k0 = ks * CK;
  float4 a0 = make_float4(0,0,0,0), a1 = make_float4(0,0,0,0);
  const float4* Wp = (const float4*)W;
  for (int kk = 0; kk < CK; ++kk) {
    int k = k0 + kk;
    float4 wv = Wp[(size_t)k * nj + j4];
    float f0 = in[k], f1 = in[K + k];
    a0.x = fmaf(f0, wv.x, a0.x); a0.y = fmaf(f0, wv.y, a0.y);
    a0.z = fmaf(f0, wv.z, a0.z); a0.w = fmaf(f0, wv.w, a0.w);
    a1.x = fmaf(f1, wv.x, a1.x); a1.y = fmaf(f1, wv.y, a1.y);
    a1.z = fmaf(f1, wv.z, a1.z); a1.w = fmaf(f1, wv.w, a1.w);
  }
  ((float4*)part)[(size_t)(ks*2 + 0) * nj + j4] = a0;
  ((float4*)part)[(size_t)(ks*2 + 1) * nj + j4] = a1;
}

__global__ __launch_bounds__(256) void fc_reduce(
    const float* __restrict__ part, const float* __restrict__ bias,
    float* __restrict__ out, int N, int KS, int relu)
{
  int t = blockIdx.x * 256 + threadIdx.x;    // t < 2N
  int b = t / N, j = t - b*N;
  float s = bias[j];
  for (int ks = 0; ks < KS; ++ks) s += part[(size_t)(ks*2 + b) * N + j];
  if (relu) s = fmaxf(s, 0.f);
  out[(size_t)b*N + j] = s;
}

// ---------------- launch ----------------
extern "C" void kernel_launch(void* const* d_in, const int* in_sizes, int n_in,
                              void* d_out, int out_size, void* d_ws, size_t ws_size,
                              hipStream_t stream) {
  const float* x    = (const float*)d_in[0];
  const float* c1w  = (const float*)d_in[1];
  const float* c1b  = (const float*)d_in[2];
  const float* bn1  = (const float*)d_in[3];
  const float* ppw  = (const float*)d_in[4];
  const float* ppb  = (const float*)d_in[5];
  const float* paw  = (const float*)d_in[6];
  const float* pab  = (const float*)d_in[7];
  const float* bn2  = (const float*)d_in[8];
  const float* ccw1 = (const float*)d_in[9];
  const float* cba1 = (const float*)d_in[10];
  const float* cbu1 = (const float*)d_in[11];
  const float* bn3  = (const float*)d_in[12];
  const float* ccw2 = (const float*)d_in[13];
  const float* cba2 = (const float*)d_in[14];
  const float* cbu2 = (const float*)d_in[15];
  const float* bn4  = (const float*)d_in[16];
  const float* dcw  = (const float*)d_in[17];
  const float* dcba = (const float*)d_in[18];
  const float* dcbu = (const float*)d_in[19];
  const float* w1   = (const float*)d_in[20];
  const float* b1   = (const float*)d_in[21];
  const float* w2   = (const float*)d_in[22];
  const float* b2   = (const float*)d_in[23];
  const float* w3   = (const float*)d_in[24];
  const float* b3   = (const float*)d_in[25];

  float* ws    = (float*)d_ws;
  float* h     = ws + O_H;
  float* pose2 = ws + O_POSE2;
  float* act2  = ws + O_ACT2;
  float* pose3 = ws + O_POSE3;
  float* act3  = ws + O_ACT3;
  float* pose4 = ws + O_POSE4;
  float* act4  = ws + O_ACT4;
  float* decin = ws + O_DECIN;
  float* h1    = ws + O_H1;
  float* h2    = ws + O_H2;
  float* part  = ws + O_PART;

  // 1) conv1 + relu + bn1
  conv1_k<<<3072, 256, 0, stream>>>(x, c1w, c1b, bn1, h);
  // 2) primary caps: pose conv (BN2 folded) + act conv (sigmoid)
  conv2_gemm<<<dim3(25, 9), 256, 0, stream>>>(h, ppw, ppb, paw, pab, bn2, pose2, act2);
  // 3) ConvCaps1 (28->13), BN3 folded
  routing_k<288, 4, true><<<338, 256, 0, stream>>>(pose2, act2, ccw1, cba1, cbu1, bn3,
                                                   pose3, act3, 28, 28, 13);
  // 4) ConvCaps2 (13->6), BN4 folded
  routing_k<288, 4, true><<<72, 256, 0, stream>>>(pose3, act3, ccw2, cba2, cbu2, bn4,
                                                  pose4, act4, 13, 13, 6);
  // 5) DenseCaps -> dec_in [2,512]
  routing_k<1152, 8, false><<<2, 512, 0, stream>>>(pose4, act4, dcw, dcba, dcbu, nullptr,
                                                   decin, nullptr, 0, 0, 0);
  // 6) decoder
  fc_partial<<<8, 256, 0, stream>>>(decin, w1, part, 512, 512, 32);
  fc_reduce<<<4, 256, 0, stream>>>(part, b1, h1, 512, 16, 1);
  fc_partial<<<16, 256, 0, stream>>>(h1, w2, part, 512, 1024, 32);
  fc_reduce<<<8, 256, 0, stream>>>(part, b2, h2, 1024, 16, 1);
  fc_partial<<<64, 256, 0, stream>>>(h2, w3, part, 1024, 8192, 128);
  fc_reduce<<<64, 256, 0, stream>>>(part, b3, (float*)d_out, 8192, 8, 0);
}

// Round 2
// 825.480 us; speedup vs baseline: 1.5589x; 1.5589x over previous
//
#include <hip/hip_runtime.h>
#include <hip/hip_bf16.h>

#define EPSR 1e-8f
#define BNEPS 1e-3f
#define LOG2PI 1.8378770664093453f

// ---------------- ws layout (float offsets) ----------------
#define O_H      0          // h:     2*64*64*96   = 786432   (dead after conv2 -> reused for dense scratch)
#define O_POSE2  786432     // pose2: 2*28*28*512  = 802816
#define O_ACT2   1589248    // act2:  2*28*28*32   = 50176
#define O_POSE3  1639424    // pose3: 2*13*13*512  = 173056
#define O_ACT3   1812480    // act3:  2*13*13*32   = 10816
#define O_POSE4  1823296    // pose4: 2*6*6*512    = 36864
#define O_ACT4   1860160    // act4:  2*6*6*32     = 2304
#define O_DECIN  1862464    // 2*512
#define O_H1     1863488    // 2*512
#define O_H2     1864512    // 2*1024
#define O_PART   1866560    // max 8*2*8192 = 131072
// dense routing scratch reuses O_H:
#define O_DSTAT  0          // 24 * 1056 = 25344 floats
#define O_DCOMB  32768      // 2 * 1088 floats

// ---------------- conv1: 11x11 s2 SAME 3->96 + bias + relu + BN1 ----------------
__global__ __launch_bounds__(256) void conv1_k(
    const float* __restrict__ x, const float* __restrict__ w,
    const float* __restrict__ bias, const float* __restrict__ bn1,
    float* __restrict__ h)
{
  int t = blockIdx.x * 256 + threadIdx.x;        // 786432 total
  int c = t % 96; int px = t / 96;
  int ox = px & 63; int r = px >> 6; int oy = r & 63; int b = r >> 6;
  float acc = 0.f;
  int iy0 = 2*oy - 4, ix0 = 2*ox - 4;
  for (int ky = 0; ky < 11; ++ky) {
    int iy = iy0 + ky;
    if ((unsigned)iy > 127u) continue;
    const float* xrow = x + (size_t)((b*128 + iy)*128)*3;
    const float* wrow = w + (ky*11*3)*96 + c;
    for (int kx = 0; kx < 11; ++kx) {
      int ix = ix0 + kx;
      if ((unsigned)ix > 127u) continue;
      const float* xp = xrow + ix*3;
      const float* wp = wrow + kx*3*96;
      acc = fmaf(xp[0], wp[0],   acc);
      acc = fmaf(xp[1], wp[96],  acc);
      acc = fmaf(xp[2], wp[192], acc);
    }
  }
  acc += bias[c];
  acc = fmaxf(acc, 0.f);
  float g = bn1[c], be = bn1[96+c], mm = bn1[192+c], vv = bn1[288+c];
  h[t] = (acc - mm) * (g * rsqrtf(vv + BNEPS)) + be;
}

// ---------------- zero raw accumulators ----------------
__global__ __launch_bounds__(256) void zero_raw(float* __restrict__ pose2, float* __restrict__ act2)
{
  int t = blockIdx.x * 256 + threadIdx.x;   // 852992 total
  if (t < 802816) pose2[t] = 0.f;
  else act2[t - 802816] = 0.f;
}

// ---------------- primary caps conv as implicit GEMM, K-split x6 ----------------
// A: im2col of h -> [1568][7776], B: weights [7776][512 pose | 32 act]
// grid (25, 9, 6); each z owns 81 of the 486 k-tiles; atomicAdd partials into raw buffers.
__global__ __launch_bounds__(256) void conv2_gemm_ks(
    const float* __restrict__ h,
    const float* __restrict__ pw, const float* __restrict__ aw,
    float* __restrict__ pose2r, float* __restrict__ act2r)
{
  __shared__ float As[2][16][68];
  __shared__ float Bs[2][16][68];
  const int tid = threadIdx.x;
  const int mb = blockIdx.x, nb = blockIdx.y, z = blockIdx.z;
  const int m0 = mb * 64;
  const float* Bp; int ldB, n0;
  if (nb < 8) { Bp = pw; ldB = 512; n0 = nb * 64; } else { Bp = aw; ldB = 32; n0 = 0; }

  const int a_ml = tid & 63, a_cig = tid >> 6;
  const int am = m0 + a_ml;
  const bool am_ok = am < 1568;
  int ab_ = am / 784; int ayx = am - ab_*784;
  int aoy = ayx / 28, aox = ayx - aoy*28;
  if (!am_ok) { ab_ = 0; aoy = 0; aox = 0; }
  const float* a_base = h + (size_t)((ab_*64 + 2*aoy)*64 + 2*aox)*96 + a_cig*4;

  const int b_kk = tid >> 4, b_ng = tid & 15;
  const int b_col = b_ng * 4;
  const bool b_ok = b_col < ldB;

  const int tm = (tid & 15) * 4, tn = (tid >> 4) * 4;
  float acc[4][4] = {{0}};

  auto kidx = [](int kt, int& ky, int& kx, int& ci0) {
    int cig = kt % 6; int r = kt / 6; kx = r % 9; ky = r / 9; ci0 = cig * 16;
  };
  auto ldAv = [&](int ky, int kx, int ci0) -> float4 {
    if (!am_ok) return make_float4(0,0,0,0);
    return *(const float4*)(a_base + (ky*64 + kx)*96 + ci0);
  };
  auto ldBv = [&](int kt) -> float4 {
    if (!b_ok) return make_float4(0,0,0,0);
    return *(const float4*)(Bp + (size_t)(kt*16 + b_kk) * ldB + n0 + b_col);
  };
  auto wrAv = [&](float4 v, int buf) {
    As[buf][a_cig*4+0][a_ml] = v.x;
    As[buf][a_cig*4+1][a_ml] = v.y;
    As[buf][a_cig*4+2][a_ml] = v.z;
    As[buf][a_cig*4+3][a_ml] = v.w;
  };
  auto wrBv = [&](float4 v, int buf) {
    *(float4*)&Bs[buf][b_kk][b_col] = v;
  };

  const int kt0 = z * 81;
  {
    int ky, kx, ci0; kidx(kt0, ky, kx, ci0);
    wrAv(ldAv(ky, kx, ci0), 0); wrBv(ldBv(kt0), 0);
  }
  __syncthreads();

  for (int i = 0; i < 81; ++i) {
    int cur = i & 1;
    bool st = i < 80;
    float4 va, vb;
    if (st) {
      int ky, kx, ci0; kidx(kt0 + i + 1, ky, kx, ci0);
      va = ldAv(ky, kx, ci0);
      vb = ldBv(kt0 + i + 1);
    }
    #pragma unroll
    for (int kk = 0; kk < 16; ++kk) {
      float4 av = *(const float4*)&As[cur][kk][tm];
      float4 bv = *(const float4*)&Bs[cur][kk][tn];
      float aa[4] = {av.x, av.y, av.z, av.w};
      float bb4[4] = {bv.x, bv.y, bv.z, bv.w};
      #pragma unroll
      for (int ii = 0; ii < 4; ++ii)
        #pragma unroll
        for (int jj = 0; jj < 4; ++jj)
          acc[ii][jj] = fmaf(aa[ii], bb4[jj], acc[ii][jj]);
    }
    if (st) { wrAv(va, cur ^ 1); wrBv(vb, cur ^ 1); }
    __syncthreads();
  }

  #pragma unroll
  for (int i = 0; i < 4; ++i) {
    int m = m0 + tm + i;
    if (m >= 1568) break;
    #pragma unroll
    for (int j = 0; j < 4; ++j) {
      int nl = tn + j;
      if (nb < 8) {
        atomicAdd(&pose2r[(size_t)m*512 + n0 + nl], acc[i][j]);
      } else if (nl < 32) {
        atomicAdd(&act2r[(size_t)m*32 + nl], acc[i][j]);
      }
    }
  }
}

// ---------------- conv2 epilogue: bias + BN2 (pose) / bias + sigmoid (act), in-place ----------------
__global__ __launch_bounds__(256) void conv2_epi(
    const float* __restrict__ pb, const float* __restrict__ ab,
    const float* __restrict__ bn2,
    float* __restrict__ pose2, float* __restrict__ act2)
{
  int t = blockIdx.x * 256 + threadIdx.x;   // 852992 total
  if (t < 802816) {
    int n = t & 511;
    float val = pose2[t] + pb[n];
    int caps = n >> 4;
    float g = bn2[caps], be = bn2[32+caps], mm = bn2[64+caps], vv = bn2[96+caps];
    pose2[t] = (val - mm) * (g * rsqrtf(vv + BNEPS)) + be;
  } else {
    int t2 = t - 802816;
    int nl = t2 & 31;
    float val = act2[t2] + ab[nl];
    act2[t2] = 1.f / (1.f + expf(-val));
  }
}

// ---------------- fused votes + EM routing (conv caps) ----------------
template<int NIN, int NWAVES, bool CONV>
__global__ __launch_bounds__(NWAVES*64) void routing_k(
    const float* __restrict__ pose_in, const float* __restrict__ act_in,
    const float* __restrict__ Wv,
    const float* __restrict__ ba, const float* __restrict__ bu,
    const float* __restrict__ bn,
    float* __restrict__ pose_out, float* __restrict__ act_out,
    int Hin, int Win, int Wout)
{
  constexpr int NT  = NWAVES * 64;
  constexpr int NPW = NIN / NWAVES;
  __shared__ float s1s[NWAVES][32*17];
  __shared__ float s2s[NWAVES][32*17];
  __shared__ float rsP[NWAVES][32];
  __shared__ float muS[32*17], isgS[32*17], lgS[32*17];
  __shared__ float laS[32], lsS[32], aoS[32], RsS[32], S0S[32];

  const int tid = threadIdx.x;
  const int wv = tid >> 6, lane = tid & 63;
  const int o = lane & 31, half = lane >> 5;

  int bb = 0, oy = 0, ox = 0;
  if (CONV) {
    int px = blockIdx.x;
    ox = px % Wout; int t2 = px / Wout; oy = t2 % Wout; bb = t2 / Wout;
  } else {
    bb = blockIdx.x;
  }

  float mur[8], isgr[8], lar = 0.f, lsr = 0.f;
  #pragma unroll
  for (int i = 0; i < 8; ++i) { mur[i] = 0.f; isgr[i] = 0.f; }

  for (int p = 0; p < 3; ++p) {
    float lam = 0.01f * (float)(p + 1);
    float s1r[8] = {0,0,0,0,0,0,0,0};
    float s2r[8] = {0,0,0,0,0,0,0,0};
    float rsr = 0.f;

    for (int it = 0; it < NPW; ++it) {
      int n = wv * NPW + it;
      const float* wp = Wv + (size_t)(n*32 + o) * 16;
      float4 w0 = *(const float4*)(wp);
      float4 w1 = *(const float4*)(wp + 4);
      float4 w2 = *(const float4*)(wp + 8);
      float4 w3 = *(const float4*)(wp + 12);
      const float* pp; float an;
      if (CONV) {
        int c = n & 31, kk = n >> 5;
        int ki = kk / 3, kj = kk - ki*3;
        int pix = (bb*Hin + 2*oy + ki)*Win + 2*ox + kj;
        pp = pose_in + (size_t)(pix*32 + c) * 16;
        an = act_in[pix*32 + c];
      } else {
        pp = pose_in + (size_t)(bb*NIN + n) * 16;
        an = act_in[bb*NIN + n];
      }
      float4 p0 = *(const float4*)(pp + half*8);
      float4 p1 = *(const float4*)(pp + half*8 + 4);
      float v[8];
      v[0] = fmaf(p0.x,w0.x, fmaf(p0.y,w1.x, fmaf(p0.z,w2.x, p0.w*w3.x)));
      v[1] = fmaf(p0.x,w0.y, fmaf(p0.y,w1.y, fmaf(p0.z,w2.y, p0.w*w3.y)));
      v[2] = fmaf(p0.x,w0.z, fmaf(p0.y,w1.z, fmaf(p0.z,w2.z, p0.w*w3.z)));
      v[3] = fmaf(p0.x,w0.w, fmaf(p0.y,w1.w, fmaf(p0.z,w2.w, p0.w*w3.w)));
      v[4] = fmaf(p1.x,w0.x, fmaf(p1.y,w1.x, fmaf(p1.z,w2.x, p1.w*w3.x)));
      v[5] = fmaf(p1.x,w0.y, fmaf(p1.y,w1.y, fmaf(p1.z,w2.y, p1.w*w3.y)));
      v[6] = fmaf(p1.x,w0.z, fmaf(p1.y,w1.z, fmaf(p1.z,w2.z, p1.w*w3.z)));
      v[7] = fmaf(p1.x,w0.w, fmaf(p1.y,w1.w, fmaf(p1.z,w2.w, p1.w*w3.w)));

      float R;
      if (p == 0) {
        R = 1.f / 32.f;
      } else {
        float t = 0.f;
        #pragma unroll
        for (int dd = 0; dd < 8; ++dd) { float df = v[dd] - mur[dd]; t = fmaf(df*df, isgr[dd], t); }
        t += __shfl_xor(t, 32, 64);
        float logit = lar - 0.5f * (t + lsr);
        float mx = logit;
        mx = fmaxf(mx, __shfl_xor(mx, 16, 64));
        mx = fmaxf(mx, __shfl_xor(mx,  8, 64));
        mx = fmaxf(mx, __shfl_xor(mx,  4, 64));
        mx = fmaxf(mx, __shfl_xor(mx,  2, 64));
        mx = fmaxf(mx, __shfl_xor(mx,  1, 64));
        float e = expf(logit - mx);
        float se = e;
        se += __shfl_xor(se, 16, 64);
        se += __shfl_xor(se,  8, 64);
        se += __shfl_xor(se,  4, 64);
        se += __shfl_xor(se,  2, 64);
        se += __shfl_xor(se,  1, 64);
        R = e / se;
      }
      float Ra = R * an;
      rsr += Ra;
      #pragma unroll
      for (int dd = 0; dd < 8; ++dd) {
        s1r[dd] = fmaf(Ra, v[dd], s1r[dd]);
        s2r[dd] = fmaf(Ra * v[dd], v[dd], s2r[dd]);
      }
    }

    #pragma unroll
    for (int dd = 0; dd < 8; ++dd) {
      s1s[wv][o*17 + half*8 + dd] = s1r[dd];
      s2s[wv][o*17 + half*8 + dd] = s2r[dd];
    }
    if (!half) rsP[wv][o] = rsr;
    __syncthreads();
    if (tid < 32) {
      float r = 0.f;
      #pragma unroll
      for (int w2 = 0; w2 < NWAVES; ++w2) r += rsP[w2][tid];
      S0S[tid] = r; RsS[tid] = r + EPSR;
    }
    __syncthreads();
    for (int idx = tid; idx < 512; idx += NT) {
      int oo = idx >> 4, d = idx & 15;
      float S1 = 0.f, S2 = 0.f;
      #pragma unroll
      for (int w2 = 0; w2 < NWAVES; ++w2) { S1 += s1s[w2][oo*17+d]; S2 += s2s[w2][oo*17+d]; }
      float Rs = RsS[oo];
      float m_ = S1 / Rs;
      float sg = (S2 - 2.f*m_*S1 + m_*m_*S0S[oo]) / Rs + EPSR;
      muS[oo*17+d]  = m_;
      isgS[oo*17+d] = 1.f / sg;
      lgS[oo*17+d]  = logf(sg);
    }
    __syncthreads();
    if (tid < 32) {
      float L = 0.f;
      #pragma unroll
      for (int d = 0; d < 16; ++d) L += lgS[tid*17 + d];
      float cost = (16.f*bu[tid] + 0.5f*L) * RsS[tid];
      float av = 1.f / (1.f + expf(-lam * (ba[tid] - cost)));
      aoS[tid] = av;
      laS[tid] = logf(av + EPSR);
      lsS[tid] = 16.f*LOG2PI + L;
    }
    __syncthreads();
    if (p < 2) {
      #pragma unroll
      for (int dd = 0; dd < 8; ++dd) {
        mur[dd]  = muS[o*17 + half*8 + dd];
        isgr[dd] = isgS[o*17 + half*8 + dd];
      }
      lar = laS[o]; lsr = lsS[o];
    }
  }

  if (CONV) {
    int pxo = (bb*Wout + oy)*Wout + ox;
    for (int idx = tid; idx < 512; idx += NT) {
      int oo = idx >> 4, d = idx & 15;
      float val = muS[oo*17 + d];
      float g = bn[oo], be = bn[32+oo], mm = bn[64+oo], vv = bn[96+oo];
      val = (val - mm) * (g * rsqrtf(vv + BNEPS)) + be;
      pose_out[(size_t)pxo*512 + idx] = val;
    }
    if (tid < 32) act_out[(size_t)pxo*32 + tid] = aoS[tid];
  } else {
    for (int idx = tid; idx < 512; idx += NT)
      pose_out[(size_t)bb*512 + idx] = muS[(idx>>4)*17 + (idx&15)];
  }
}

// ---------------- dense caps: per-pass stats (many blocks) + combine ----------------
// stats layout per (b,chunk): s1[512], s2[512], s0[32] -> 1056 floats
// comb layout per b: mu[512], isg[512], la[32], ls[32] -> 1088 floats
template<int P>
__global__ __launch_bounds__(256) void dense_stats(
    const float* __restrict__ pose_in, const float* __restrict__ act_in,
    const float* __restrict__ Wv, const float* __restrict__ comb,
    float* __restrict__ stat)
{
  __shared__ float s1s[4][32*17];
  __shared__ float s2s[4][32*17];
  __shared__ float rsP[4][32];
  const int tid = threadIdx.x;
  const int wv = tid >> 6, lane = tid & 63;
  const int o = lane & 31, half = lane >> 5;
  const int bb = blockIdx.x / 12, chunk = blockIdx.x % 12;

  float mur[8], isgr[8], lar = 0.f, lsr = 0.f;
  if (P > 0) {
    const float* cb = comb + (size_t)bb * 1088;
    #pragma unroll
    for (int dd = 0; dd < 8; ++dd) {
      mur[dd]  = cb[o*16 + half*8 + dd];
      isgr[dd] = cb[512 + o*16 + half*8 + dd];
    }
    lar = cb[1024 + o]; lsr = cb[1056 + o];
  }

  float s1r[8] = {0,0,0,0,0,0,0,0};
  float s2r[8] = {0,0,0,0,0,0,0,0};
  float rsr = 0.f;

  for (int it = 0; it < 24; ++it) {
    int n = chunk*96 + wv*24 + it;
    const float* wp = Wv + (size_t)(n*32 + o) * 16;
    float4 w0 = *(const float4*)(wp);
    float4 w1 = *(const float4*)(wp + 4);
    float4 w2 = *(const float4*)(wp + 8);
    float4 w3 = *(const float4*)(wp + 12);
    const float* pp = pose_in + (size_t)(bb*1152 + n) * 16;
    float an = act_in[bb*1152 + n];
    float4 p0 = *(const float4*)(pp + half*8);
    float4 p1 = *(const float4*)(pp + half*8 + 4);
    float v[8];
    v[0] = fmaf(p0.x,w0.x, fmaf(p0.y,w1.x, fmaf(p0.z,w2.x, p0.w*w3.x)));
    v[1] = fmaf(p0.x,w0.y, fmaf(p0.y,w1.y, fmaf(p0.z,w2.y, p0.w*w3.y)));
    v[2] = fmaf(p0.x,w0.z, fmaf(p0.y,w1.z, fmaf(p0.z,w2.z, p0.w*w3.z)));
    v[3] = fmaf(p0.x,w0.w, fmaf(p0.y,w1.w, fmaf(p0.z,w2.w, p0.w*w3.w)));
    v[4] = fmaf(p1.x,w0.x, fmaf(p1.y,w1.x, fmaf(p1.z,w2.x, p1.w*w3.x)));
    v[5] = fmaf(p1.x,w0.y, fmaf(p1.y,w1.y, fmaf(p1.z,w2.y, p1.w*w3.y)));
    v[6] = fmaf(p1.x,w0.z, fmaf(p1.y,w1.z, fmaf(p1.z,w2.z, p1.w*w3.z)));
    v[7] = fmaf(p1.x,w0.w, fmaf(p1.y,w1.w, fmaf(p1.z,w2.w, p1.w*w3.w)));

    float R;
    if (P == 0) {
      R = 1.f / 32.f;
    } else {
      float t = 0.f;
      #pragma unroll
      for (int dd = 0; dd < 8; ++dd) { float df = v[dd] - mur[dd]; t = fmaf(df*df, isgr[dd], t); }
      t += __shfl_xor(t, 32, 64);
      float logit = lar - 0.5f * (t + lsr);
      float mx = logit;
      mx = fmaxf(mx, __shfl_xor(mx, 16, 64));
      mx = fmaxf(mx, __shfl_xor(mx,  8, 64));
      mx = fmaxf(mx, __shfl_xor(mx,  4, 64));
      mx = fmaxf(mx, __shfl_xor(mx,  2, 64));
      mx = fmaxf(mx, __shfl_xor(mx,  1, 64));
      float e = expf(logit - mx);
      float se = e;
      se += __shfl_xor(se, 16, 64);
      se += __shfl_xor(se,  8, 64);
      se += __shfl_xor(se,  4, 64);
      se += __shfl_xor(se,  2, 64);
      se += __shfl_xor(se,  1, 64);
      R = e / se;
    }
    float Ra = R * an;
    rsr += Ra;
    #pragma unroll
    for (int dd = 0; dd < 8; ++dd) {
      s1r[dd] = fmaf(Ra, v[dd], s1r[dd]);
      s2r[dd] = fmaf(Ra * v[dd], v[dd], s2r[dd]);
    }
  }

  #pragma unroll
  for (int dd = 0; dd < 8; ++dd) {
    s1s[wv][o*17 + half*8 + dd] = s1r[dd];
    s2s[wv][o*17 + half*8 + dd] = s2r[dd];
  }
  if (!half) rsP[wv][o] = rsr;
  __syncthreads();

  float* out = stat + (size_t)(bb*12 + chunk) * 1056;
  for (int idx = tid; idx < 512; idx += 256) {
    int oo = idx >> 4, d = idx & 15;
    float S1 = 0.f, S2 = 0.f;
    #pragma unroll
    for (int w2 = 0; w2 < 4; ++w2) { S1 += s1s[w2][oo*17+d]; S2 += s2s[w2][oo*17+d]; }
    out[idx] = S1; out[512 + idx] = S2;
  }
  if (tid < 32) {
    float r = 0.f;
    #pragma unroll
    for (int w2 = 0; w2 < 4; ++w2) r += rsP[w2][tid];
    out[1024 + tid] = r;
  }
}

template<int P>
__global__ __launch_bounds__(256) void dense_comb(
    const float* __restrict__ stat,
    const float* __restrict__ ba, const float* __restrict__ bu,
    float* __restrict__ comb, float* __restrict__ decin)
{
  __shared__ float S0S[32], RsS[32], lgS[32*17];
  const int tid = threadIdx.x;
  const int bb = blockIdx.x;
  const float* st = stat + (size_t)bb * 12 * 1056;
  float* cb = comb + (size_t)bb * 1088;

  if (tid < 32) {
    float r = 0.f;
    #pragma unroll
    for (int c = 0; c < 12; ++c) r += st[c*1056 + 1024 + tid];
    S0S[tid] = r; RsS[tid] = r + EPSR;
  }
  __syncthreads();
  for (int idx = tid; idx < 512; idx += 256) {
    int oo = idx >> 4, d = idx & 15;
    float S1 = 0.f, S2 = 0.f;
    #pragma unroll
    for (int c = 0; c < 12; ++c) { S1 += st[c*1056 + idx]; S2 += st[c*1056 + 512 + idx]; }
    float Rs = RsS[oo];
    float m_ = S1 / Rs;
    float sg = (S2 - 2.f*m_*S1 + m_*m_*S0S[oo]) / Rs + EPSR;
    if (P == 2) {
      decin[(size_t)bb*512 + idx] = m_;
    } else {
      cb[idx] = m_;
      cb[512 + idx] = 1.f / sg;
    }
    lgS[oo*17 + d] = logf(sg);
  }
  __syncthreads();
  if (P < 2 && tid < 32) {
    float L = 0.f;
    #pragma unroll
    for (int d = 0; d < 16; ++d) L += lgS[tid*17 + d];
    float lam = 0.01f * (float)(P + 1);
    float cost = (16.f*bu[tid] + 0.5f*L) * RsS[tid];
    float av = 1.f / (1.f + expf(-lam * (ba[tid] - cost)));
    cb[1024 + tid] = logf(av + EPSR);
    cb[1056 + tid] = 16.f*LOG2PI + L;
  }
}

// ---------------- decoder FC: K-split partial + reduce ----------------
__global__ __launch_bounds__(256) void fc_partial(
    const float* __restrict__ in, const float* __restrict__ W,
    float* __restrict__ part, int K, int N, int CK)
{
  int t = blockIdx.x * 256 + threadIdx.x;
  int nj = N >> 2;
  int j4 = t % nj, ks = t / nj;
  int k0 = ks * CK;
  float4 a0 = make_float4(0,0,0,0), a1 = make_float4(0,0,0,0);
  const float4* Wp = (const float4*)W;
  for (int kk = 0; kk < CK; ++kk) {
    int k = k0 + kk;
    float4 wv = Wp[(size_t)k * nj + j4];
    float f0 = in[k], f1 = in[K + k];
    a0.x = fmaf(f0, wv.x, a0.x); a0.y = fmaf(f0, wv.y, a0.y);
    a0.z = fmaf(f0, wv.z, a0.z); a0.w = fmaf(f0, wv.w, a0.w);
    a1.x = fmaf(f1, wv.x, a1.x); a1.y = fmaf(f1, wv.y, a1.y);
    a1.z = fmaf(f1, wv.z, a1.z); a1.w = fmaf(f1, wv.w, a1.w);
  }
  ((float4*)part)[(size_t)(ks*2 + 0) * nj + j4] = a0;
  ((float4*)part)[(size_t)(ks*2 + 1) * nj + j4] = a1;
}

__global__ __launch_bounds__(256) void fc_reduce(
    const float* __restrict__ part, const float* __restrict__ bias,
    float* __restrict__ out, int N, int KS, int relu)
{
  int t = blockIdx.x * 256 + threadIdx.x;
  int b = t / N, j = t - b*N;
  float s = bias[j];
  for (int ks = 0; ks < KS; ++ks) s += part[(size_t)(ks*2 + b) * N + j];
  if (relu) s = fmaxf(s, 0.f);
  out[(size_t)b*N + j] = s;
}

// ---------------- launch ----------------
extern "C" void kernel_launch(void* const* d_in, const int* in_sizes, int n_in,
                              void* d_out, int out_size, void* d_ws, size_t ws_size,
                              hipStream_t stream) {
  const float* x    = (const float*)d_in[0];
  const float* c1w  = (const float*)d_in[1];
  const float* c1b  = (const float*)d_in[2];
  const float* bn1  = (const float*)d_in[3];
  const float* ppw  = (const float*)d_in[4];
  const float* ppb  = (const float*)d_in[5];
  const float* paw  = (const float*)d_in[6];
  const float* pab  = (const float*)d_in[7];
  const float* bn2  = (const float*)d_in[8];
  const float* ccw1 = (const float*)d_in[9];
  const float* cba1 = (const float*)d_in[10];
  const float* cbu1 = (const float*)d_in[11];
  const float* bn3  = (const float*)d_in[12];
  const float* ccw2 = (const float*)d_in[13];
  const float* cba2 = (const float*)d_in[14];
  const float* cbu2 = (const float*)d_in[15];
  const float* bn4  = (const float*)d_in[16];
  const float* dcw  = (const float*)d_in[17];
  const float* dcba = (const float*)d_in[18];
  const float* dcbu = (const float*)d_in[19];
  const float* w1   = (const float*)d_in[20];
  const float* b1   = (const float*)d_in[21];
  const float* w2   = (const float*)d_in[22];
  const float* b2   = (const float*)d_in[23];
  const float* w3   = (const float*)d_in[24];
  const float* b3   = (const float*)d_in[25];

  float* ws    = (float*)d_ws;
  float* h     = ws + O_H;
  float* pose2 = ws + O_POSE2;
  float* act2  = ws + O_ACT2;
  float* pose3 = ws + O_POSE3;
  float* act3  = ws + O_ACT3;
  float* pose4 = ws + O_POSE4;
  float* act4  = ws + O_ACT4;
  float* decin = ws + O_DECIN;
  float* h1    = ws + O_H1;
  float* h2    = ws + O_H2;
  float* part  = ws + O_PART;
  float* dstat = ws + O_DSTAT;   // reuses h region (dead by then)
  float* dcomb = ws + O_DCOMB;

  conv1_k<<<3072, 256, 0, stream>>>(x, c1w, c1b, bn1, h);
  zero_raw<<<3332, 256, 0, stream>>>(pose2, act2);
  conv2_gemm_ks<<<dim3(25, 9, 6), 256, 0, stream>>>(h, ppw, paw, pose2, act2);
  conv2_epi<<<3332, 256, 0, stream>>>(ppb, pab, bn2, pose2, act2);
  routing_k<288, 8, true><<<338, 512, 0, stream>>>(pose2, act2, ccw1, cba1, cbu1, bn3,
                                                   pose3, act3, 28, 28, 13);
  routing_k<288, 8, true><<<72, 512, 0, stream>>>(pose3, act3, ccw2, cba2, cbu2, bn4,
                                                  pose4, act4, 13, 13, 6);
  dense_stats<0><<<24, 256, 0, stream>>>(pose4, act4, dcw, nullptr, dstat);
  dense_comb<0><<<2, 256, 0, stream>>>(dstat, dcba, dcbu, dcomb, nullptr);
  dense_stats<1><<<24, 256, 0, stream>>>(pose4, act4, dcw, dcomb, dstat);
  dense_comb<1><<<2, 256, 0, stream>>>(dstat, dcba, dcbu, dcomb, nullptr);
  dense_stats<2><<<24, 256, 0, stream>>>(pose4, act4, dcw, dcomb, dstat);
  dense_comb<2><<<2, 256, 0, stream>>>(dstat, dcba, dcbu, dcomb, decin);
  fc_partial<<<8, 256, 0, stream>>>(decin, w1, part, 512, 512, 32);
  fc_reduce<<<4, 256, 0, stream>>>(part, b1, h1, 512, 16, 1);
  fc_partial<<<16, 256, 0, stream>>>(h1, w2, part, 512, 1024, 32);
  fc_reduce<<<8, 256, 0, stream>>>(part, b2, h2, 1024, 16, 1);
  fc_partial<<<64, 256, 0, stream>>>(h2, w3, part, 1024, 8192, 128);
  fc_reduce<<<64, 256, 0, stream>>>(part, b3, (float*)d_out, 8192, 8, 0);
}

// Round 4
// 696.678 us; speedup vs baseline: 1.8471x; 1.1849x over previous
//
#include <hip/hip_runtime.h>
#include <hip/hip_bf16.h>

#define EPSR 1e-8f
#define BNEPS 1e-3f
#define LOG2PI 1.8378770664093453f

typedef _Float16 f16;
typedef _Float16 f16x4 __attribute__((ext_vector_type(4)));
typedef _Float16 f16x8 __attribute__((ext_vector_type(8)));
typedef float f32x4 __attribute__((ext_vector_type(4)));

// ---------------- ws layout (float offsets) ----------------
#define O_H      0          // fast: h_hi/h_lo f16 (2*786432 f16); fallback: h fp32 786432
#define O_POSE2  786432     // pose2: 2*28*28*512  = 802816
#define O_ACT2   1589248    // act2:  2*28*28*32   = 50176
#define O_POSE3  1639424    // pose3: 2*13*13*512  = 173056
#define O_ACT3   1812480    // act3:  2*13*13*32   = 10816
#define O_POSE4  1823296    // pose4: 2*6*6*512    = 36864
#define O_ACT4   1860160    // act4:  2*6*6*32     = 2304
#define O_DECIN  1862464    // 2*512
#define O_H1     1863488    // 2*512
#define O_H2     1864512    // 2*1024
#define O_PART   1866560    // max 8*2*8192 = 131072  (ends 1997632)
#define O_BWH    1997632    // Bw_hi f16 [640][7776] = 4976640 f16 = 2488320 floats
#define O_BWL    4485952    // Bw_lo  -> ends 6974272 floats
#define NEED_BYTES (6974272ull * 4ull)
// dense routing scratch reuses O_H (dead after conv2):
#define O_DSTAT  0          // 24 * 1056 floats
#define O_DCOMB  32768      // 2 * 1088 floats

// ---------------- conv1: 11x11 s2 SAME 3->96 + bias + relu + BN1 ----------------
template<int F16>
__global__ __launch_bounds__(256) void conv1_k(
    const float* __restrict__ x, const float* __restrict__ w,
    const float* __restrict__ bias, const float* __restrict__ bn1,
    float* __restrict__ h32, f16* __restrict__ hh, f16* __restrict__ hl)
{
  int t = blockIdx.x * 256 + threadIdx.x;        // 786432 total
  int c = t % 96; int px = t / 96;
  int ox = px & 63; int r = px >> 6; int oy = r & 63; int b = r >> 6;
  float acc = 0.f;
  int iy0 = 2*oy - 4, ix0 = 2*ox - 4;
  for (int ky = 0; ky < 11; ++ky) {
    int iy = iy0 + ky;
    if ((unsigned)iy > 127u) continue;
    const float* xrow = x + (size_t)((b*128 + iy)*128)*3;
    const float* wrow = w + (ky*11*3)*96 + c;
    for (int kx = 0; kx < 11; ++kx) {
      int ix = ix0 + kx;
      if ((unsigned)ix > 127u) continue;
      const float* xp = xrow + ix*3;
      const float* wp = wrow + kx*3*96;
      acc = fmaf(xp[0], wp[0],   acc);
      acc = fmaf(xp[1], wp[96],  acc);
      acc = fmaf(xp[2], wp[192], acc);
    }
  }
  acc += bias[c];
  acc = fmaxf(acc, 0.f);
  float g = bn1[c], be = bn1[96+c], mm = bn1[192+c], vv = bn1[288+c];
  float val = (acc - mm) * (g * rsqrtf(vv + BNEPS)) + be;
  if (F16) {
    f16 hi = (f16)val;
    f16 lo = (f16)(val - (float)hi);
    hh[t] = hi; hl[t] = lo;
  } else {
    h32[t] = val;
  }
}

// ---------------- weight transpose + f16 split: Bw[640][7776] hi/lo ----------------
// cols 0-511 = pw, 512-543 = aw, 544-639 = zero pad
__global__ __launch_bounds__(256) void split_w_k(
    const float* __restrict__ pw, const float* __restrict__ aw,
    f16* __restrict__ bwh, f16* __restrict__ bwl)
{
  __shared__ float tile[32][33];
  const int kb = blockIdx.x * 32, nb = blockIdx.y * 32;
  const int t = threadIdx.x;
  #pragma unroll
  for (int p = 0; p < 4; ++p) {
    int k_l = p*8 + (t>>5), n_l = t & 31;
    int k = kb + k_l, n = nb + n_l;
    float v = 0.f;
    if (n < 512) v = pw[(size_t)k*512 + n];
    else if (n < 544) v = aw[(size_t)k*32 + (n - 512)];
    tile[k_l][n_l] = v;
  }
  __syncthreads();
  #pragma unroll
  for (int p = 0; p < 4; ++p) {
    int n_l = p*8 + (t>>5), k_l = t & 31;
    float v = tile[k_l][n_l];
    f16 hi = (f16)v;
    f16 lo = (f16)(v - (float)hi);
    size_t dst = (size_t)(nb + n_l)*7776 + kb + k_l;
    bwh[dst] = hi; bwl[dst] = lo;
  }
}

// ---------------- zero raw accumulators ----------------
__global__ __launch_bounds__(256) void zero_raw(float* __restrict__ pose2, float* __restrict__ act2)
{
  int t = blockIdx.x * 256 + threadIdx.x;   // 852992 total
  if (t < 802816) pose2[t] = 0.f;
  else act2[t - 802816] = 0.f;
}

// ---------------- conv2 as fp16-split (3-MFMA) GEMM ----------------
// C[1664][640] = A[1664][7776] x B[7776][640]; A = im2col(h) hi/lo, B = Bw^T hi/lo.
// Block 128x128, BK=32, 4 waves (2x2), wave tile 64x64 (4x4 of 16x16x32 MFMA).
// grid (13, 5, 8); z = K-split; atomicAdd into raw accumulators.
// LDS slot swizzle: elem (row,k) -> row*32 + (((k>>3) + (row>>1))&3)*8 + (k&7)
//   row*16%32 has period 2 in banks; (row>>1) makes even rows cycle all 4 slots
//   -> 8 distinct start banks, 2 lanes each = 2-way (free, m136).
__global__ __launch_bounds__(256, 2) void conv2_mfma(
    const f16* __restrict__ hh, const f16* __restrict__ hl,
    const f16* __restrict__ bwh, const f16* __restrict__ bwl,
    float* __restrict__ pose2r, float* __restrict__ act2r)
{
  __shared__ f16 Ah[128*32];
  __shared__ f16 Al[128*32];
  __shared__ f16 Bh[128*32];
  __shared__ f16 Bl[128*32];
  const int tid = threadIdx.x;
  const int mb = blockIdx.x, nb = blockIdx.y, z = blockIdx.z;
  const int m0 = mb*128, n0 = nb*128;
  const int q = 243 / 8, rch = 243 % 8;             // 30 rem 3
  const int k0 = z*q + (z < rch ? z : rch);
  const int k1 = k0 + q + (z < rch ? 1 : 0);

  // staging mapping: srow 0..31, c 0..7 (k = c*4..c*4+3); 4 passes cover 128 rows
  const int srow = tid >> 3;
  const int c    = tid & 7;
  int habase[4]; bool amok[4];
  #pragma unroll
  for (int p = 0; p < 4; ++p) {
    int m = m0 + p*32 + srow;
    amok[p] = m < 1568;
    int mm = amok[p] ? m : 0;
    int b = mm / 784; int yx = mm - b*784; int oy = yx / 28, ox = yx - oy*28;
    habase[p] = ((b*64 + 2*oy)*64 + 2*ox)*96;
  }
  size_t bbase[4];
  #pragma unroll
  for (int p = 0; p < 4; ++p) bbase[p] = (size_t)(n0 + p*32 + srow) * 7776;

  f16x4 rah[4], ral[4], rbh[4], rbl[4];
  const f16x4 zv = {(f16)0, (f16)0, (f16)0, (f16)0};

  auto load_step = [&](int kt) {
    int ky = kt / 27, rr = kt % 27; int kx = rr / 3, ci0 = (rr % 3) * 32;
    int aoff = (ky*64 + kx)*96 + ci0 + c*4;
    int koff = kt*32 + c*4;
    #pragma unroll
    for (int p = 0; p < 4; ++p) {
      if (amok[p]) {
        rah[p] = *(const f16x4*)(hh + habase[p] + aoff);
        ral[p] = *(const f16x4*)(hl + habase[p] + aoff);
      } else { rah[p] = zv; ral[p] = zv; }
      rbh[p] = *(const f16x4*)(bwh + bbase[p] + koff);
      rbl[p] = *(const f16x4*)(bwl + bbase[p] + koff);
    }
  };

  int widx[4];
  #pragma unroll
  for (int p = 0; p < 4; ++p) {
    int row = p*32 + srow;
    widx[p] = row*32 + ((((c>>1) + (row>>1)) & 3) << 3) + ((c & 1) << 2);
  }

  const int wv = tid >> 6, lane = tid & 63;
  const int wr = wv >> 1, wc = wv & 1;
  const int l15 = lane & 15, g = lane >> 4;

  f32x4 acc[4][4];
  #pragma unroll
  for (int i = 0; i < 4; ++i)
    #pragma unroll
    for (int j = 0; j < 4; ++j) acc[i][j] = (f32x4){0.f, 0.f, 0.f, 0.f};

  int aidx[4], bidx[4];
  #pragma unroll
  for (int i = 0; i < 4; ++i) {
    int arow = wr*64 + i*16 + l15;
    aidx[i] = arow*32 + (((g + (arow>>1)) & 3) << 3);
    int brow = wc*64 + i*16 + l15;
    bidx[i] = brow*32 + (((g + (brow>>1)) & 3) << 3);
  }

  load_step(k0);
  for (int kt = k0; kt < k1; ++kt) {
    __syncthreads();
    #pragma unroll
    for (int p = 0; p < 4; ++p) {
      *(f16x4*)&Ah[widx[p]] = rah[p];
      *(f16x4*)&Al[widx[p]] = ral[p];
      *(f16x4*)&Bh[widx[p]] = rbh[p];
      *(f16x4*)&Bl[widx[p]] = rbl[p];
    }
    __syncthreads();
    if (kt + 1 < k1) load_step(kt + 1);     // in flight under MFMA phase
    f16x8 ah[4], al[4], bh[4], bl[4];
    #pragma unroll
    for (int i = 0; i < 4; ++i) {
      ah[i] = *(const f16x8*)&Ah[aidx[i]];
      al[i] = *(const f16x8*)&Al[aidx[i]];
      bh[i] = *(const f16x8*)&Bh[bidx[i]];
      bl[i] = *(const f16x8*)&Bl[bidx[i]];
    }
    #pragma unroll
    for (int i = 0; i < 4; ++i)
      #pragma unroll
      for (int j = 0; j < 4; ++j) {
        acc[i][j] = __builtin_amdgcn_mfma_f32_16x16x32_f16(ah[i], bh[j], acc[i][j], 0, 0, 0);
        acc[i][j] = __builtin_amdgcn_mfma_f32_16x16x32_f16(ah[i], bl[j], acc[i][j], 0, 0, 0);
        acc[i][j] = __builtin_amdgcn_mfma_f32_16x16x32_f16(al[i], bh[j], acc[i][j], 0, 0, 0);
      }
  }

  // epilogue: C/D layout col=lane&15, row=g*4+r
  #pragma unroll
  for (int i = 0; i < 4; ++i) {
    #pragma unroll
    for (int j = 0; j < 4; ++j) {
      #pragma unroll
      for (int r2 = 0; r2 < 4; ++r2) {
        int m = m0 + wr*64 + i*16 + g*4 + r2;
        int n = n0 + wc*64 + j*16 + l15;
        if (m < 1568) {
          float val = acc[i][j][r2];
          if (n < 512) atomicAdd(&pose2r[(size_t)m*512 + n], val);
          else if (n < 544) atomicAdd(&act2r[(size_t)m*32 + (n - 512)], val);
        }
      }
    }
  }
}

// ---------------- fallback fp32 conv2 (round-2 kernel) ----------------
__global__ __launch_bounds__(256) void conv2_gemm_ks(
    const float* __restrict__ h,
    const float* __restrict__ pw, const float* __restrict__ aw,
    float* __restrict__ pose2r, float* __restrict__ act2r)
{
  __shared__ float As[2][16][68];
  __shared__ float Bs[2][16][68];
  const int tid = threadIdx.x;
  const int mb = blockIdx.x, nb = blockIdx.y, z = blockIdx.z;
  const int m0 = mb * 64;
  const float* Bp; int ldB, n0;
  if (nb < 8) { Bp = pw; ldB = 512; n0 = nb * 64; } else { Bp = aw; ldB = 32; n0 = 0; }

  const int a_ml = tid & 63, a_cig = tid >> 6;
  const int am = m0 + a_ml;
  const bool am_ok = am < 1568;
  int ab_ = am / 784; int ayx = am - ab_*784;
  int aoy = ayx / 28, aox = ayx - aoy*28;
  if (!am_ok) { ab_ = 0; aoy = 0; aox = 0; }
  const float* a_base = h + (size_t)((ab_*64 + 2*aoy)*64 + 2*aox)*96 + a_cig*4;

  const int b_kk = tid >> 4, b_ng = tid & 15;
  const int b_col = b_ng * 4;
  const bool b_ok = b_col < ldB;

  const int tm = (tid & 15) * 4, tn = (tid >> 4) * 4;
  float acc[4][4] = {{0}};

  auto kidx = [](int kt, int& ky, int& kx, int& ci0) {
    int cig = kt % 6; int r = kt / 6; kx = r % 9; ky = r / 9; ci0 = cig * 16;
  };
  auto ldAv = [&](int ky, int kx, int ci0) -> float4 {
    if (!am_ok) return make_float4(0,0,0,0);
    return *(const float4*)(a_base + (ky*64 + kx)*96 + ci0);
  };
  auto ldBv = [&](int kt) -> float4 {
    if (!b_ok) return make_float4(0,0,0,0);
    return *(const float4*)(Bp + (size_t)(kt*16 + b_kk) * ldB + n0 + b_col);
  };
  auto wrAv = [&](float4 v, int buf) {
    As[buf][a_cig*4+0][a_ml] = v.x;
    As[buf][a_cig*4+1][a_ml] = v.y;
    As[buf][a_cig*4+2][a_ml] = v.z;
    As[buf][a_cig*4+3][a_ml] = v.w;
  };
  auto wrBv = [&](float4 v, int buf) {
    *(float4*)&Bs[buf][b_kk][b_col] = v;
  };

  const int kt0 = z * 81;
  {
    int ky, kx, ci0; kidx(kt0, ky, kx, ci0);
    wrAv(ldAv(ky, kx, ci0), 0); wrBv(ldBv(kt0), 0);
  }
  __syncthreads();

  for (int i = 0; i < 81; ++i) {
    int cur = i & 1;
    bool st = i < 80;
    float4 va, vb;
    if (st) {
      int ky, kx, ci0; kidx(kt0 + i + 1, ky, kx, ci0);
      va = ldAv(ky, kx, ci0);
      vb = ldBv(kt0 + i + 1);
    }
    #pragma unroll
    for (int kk = 0; kk < 16; ++kk) {
      float4 av = *(const float4*)&As[cur][kk][tm];
      float4 bv = *(const float4*)&Bs[cur][kk][tn];
      float aa[4] = {av.x, av.y, av.z, av.w};
      float bb4[4] = {bv.x, bv.y, bv.z, bv.w};
      #pragma unroll
      for (int ii = 0; ii < 4; ++ii)
        #pragma unroll
        for (int jj = 0; jj < 4; ++jj)
          acc[ii][jj] = fmaf(aa[ii], bb4[jj], acc[ii][jj]);
    }
    if (st) { wrAv(va, cur ^ 1); wrBv(vb, cur ^ 1); }
    __syncthreads();
  }

  #pragma unroll
  for (int i = 0; i < 4; ++i) {
    int m = m0 + tm + i;
    if (m >= 1568) break;
    #pragma unroll
    for (int j = 0; j < 4; ++j) {
      int nl = tn + j;
      if (nb < 8) {
        atomicAdd(&pose2r[(size_t)m*512 + n0 + nl], acc[i][j]);
      } else if (nl < 32) {
        atomicAdd(&act2r[(size_t)m*32 + nl], acc[i][j]);
      }
    }
  }
}

// ---------------- conv2 epilogue ----------------
__global__ __launch_bounds__(256) void conv2_epi(
    const float* __restrict__ pb, const float* __restrict__ ab,
    const float* __restrict__ bn2,
    float* __restrict__ pose2, float* __restrict__ act2)
{
  int t = blockIdx.x * 256 + threadIdx.x;   // 852992 total
  if (t < 802816) {
    int n = t & 511;
    float val = pose2[t] + pb[n];
    int caps = n >> 4;
    float g = bn2[caps], be = bn2[32+caps], mm = bn2[64+caps], vv = bn2[96+caps];
    pose2[t] = (val - mm) * (g * rsqrtf(vv + BNEPS)) + be;
  } else {
    int t2 = t - 802816;
    int nl = t2 & 31;
    float val = act2[t2] + ab[nl];
    act2[t2] = 1.f / (1.f + expf(-val));
  }
}

// ---------------- fused votes + EM routing (conv caps) ----------------
template<int NIN, int NWAVES, bool CONV>
__global__ __launch_bounds__(NWAVES*64) void routing_k(
    const float* __restrict__ pose_in, const float* __restrict__ act_in,
    const float* __restrict__ Wv,
    const float* __restrict__ ba, const float* __restrict__ bu,
    const float* __restrict__ bn,
    float* __restrict__ pose_out, float* __restrict__ act_out,
    int Hin, int Win, int Wout)
{
  constexpr int NT  = NWAVES * 64;
  constexpr int NPW = NIN / NWAVES;
  __shared__ float s1s[NWAVES][32*17];
  __shared__ float s2s[NWAVES][32*17];
  __shared__ float rsP[NWAVES][32];
  __shared__ float muS[32*17], isgS[32*17], lgS[32*17];
  __shared__ float laS[32], lsS[32], aoS[32], RsS[32], S0S[32];

  const int tid = threadIdx.x;
  const int wv = tid >> 6, lane = tid & 63;
  const int o = lane & 31, half = lane >> 5;

  int bb = 0, oy = 0, ox = 0;
  if (CONV) {
    int px = blockIdx.x;
    ox = px % Wout; int t2 = px / Wout; oy = t2 % Wout; bb = t2 / Wout;
  } else {
    bb = blockIdx.x;
  }

  float mur[8], isgr[8], lar = 0.f, lsr = 0.f;
  #pragma unroll
  for (int i = 0; i < 8; ++i) { mur[i] = 0.f; isgr[i] = 0.f; }

  for (int p = 0; p < 3; ++p) {
    float lam = 0.01f * (float)(p + 1);
    float s1r[8] = {0,0,0,0,0,0,0,0};
    float s2r[8] = {0,0,0,0,0,0,0,0};
    float rsr = 0.f;

    for (int it = 0; it < NPW; ++it) {
      int n = wv * NPW + it;
      const float* wp = Wv + (size_t)(n*32 + o) * 16;
      float4 w0 = *(const float4*)(wp);
      float4 w1 = *(const float4*)(wp + 4);
      float4 w2 = *(const float4*)(wp + 8);
      float4 w3 = *(const float4*)(wp + 12);
      const float* pp; float an;
      if (CONV) {
        int cc = n & 31, kk = n >> 5;
        int ki = kk / 3, kj = kk - ki*3;
        int pix = (bb*Hin + 2*oy + ki)*Win + 2*ox + kj;
        pp = pose_in + (size_t)(pix*32 + cc) * 16;
        an = act_in[pix*32 + cc];
      } else {
        pp = pose_in + (size_t)(bb*NIN + n) * 16;
        an = act_in[bb*NIN + n];
      }
      float4 p0 = *(const float4*)(pp + half*8);
      float4 p1 = *(const float4*)(pp + half*8 + 4);
      float v[8];
      v[0] = fmaf(p0.x,w0.x, fmaf(p0.y,w1.x, fmaf(p0.z,w2.x, p0.w*w3.x)));
      v[1] = fmaf(p0.x,w0.y, fmaf(p0.y,w1.y, fmaf(p0.z,w2.y, p0.w*w3.y)));
      v[2] = fmaf(p0.x,w0.z, fmaf(p0.y,w1.z, fmaf(p0.z,w2.z, p0.w*w3.z)));
      v[3] = fmaf(p0.x,w0.w, fmaf(p0.y,w1.w, fmaf(p0.z,w2.w, p0.w*w3.w)));
      v[4] = fmaf(p1.x,w0.x, fmaf(p1.y,w1.x, fmaf(p1.z,w2.x, p1.w*w3.x)));
      v[5] = fmaf(p1.x,w0.y, fmaf(p1.y,w1.y, fmaf(p1.z,w2.y, p1.w*w3.y)));
      v[6] = fmaf(p1.x,w0.z, fmaf(p1.y,w1.z, fmaf(p1.z,w2.z, p1.w*w3.z)));
      v[7] = fmaf(p1.x,w0.w, fmaf(p1.y,w1.w, fmaf(p1.z,w2.w, p1.w*w3.w)));

      float R;
      if (p == 0) {
        R = 1.f / 32.f;
      } else {
        float t = 0.f;
        #pragma unroll
        for (int dd = 0; dd < 8; ++dd) { float df = v[dd] - mur[dd]; t = fmaf(df*df, isgr[dd], t); }
        t += __shfl_xor(t, 32, 64);
        float logit = lar - 0.5f * (t + lsr);
        float mx = logit;
        mx = fmaxf(mx, __shfl_xor(mx, 16, 64));
        mx = fmaxf(mx, __shfl_xor(mx,  8, 64));
        mx = fmaxf(mx, __shfl_xor(mx,  4, 64));
        mx = fmaxf(mx, __shfl_xor(mx,  2, 64));
        mx = fmaxf(mx, __shfl_xor(mx,  1, 64));
        float e = expf(logit - mx);
        float se = e;
        se += __shfl_xor(se, 16, 64);
        se += __shfl_xor(se,  8, 64);
        se += __shfl_xor(se,  4, 64);
        se += __shfl_xor(se,  2, 64);
        se += __shfl_xor(se,  1, 64);
        R = e / se;
      }
      float Ra = R * an;
      rsr += Ra;
      #pragma unroll
      for (int dd = 0; dd < 8; ++dd) {
        s1r[dd] = fmaf(Ra, v[dd], s1r[dd]);
        s2r[dd] = fmaf(Ra * v[dd], v[dd], s2r[dd]);
      }
    }

    #pragma unroll
    for (int dd = 0; dd < 8; ++dd) {
      s1s[wv][o*17 + half*8 + dd] = s1r[dd];
      s2s[wv][o*17 + half*8 + dd] = s2r[dd];
    }
    if (!half) rsP[wv][o] = rsr;
    __syncthreads();
    if (tid < 32) {
      float r = 0.f;
      #pragma unroll
      for (int w2 = 0; w2 < NWAVES; ++w2) r += rsP[w2][tid];
      S0S[tid] = r; RsS[tid] = r + EPSR;
    }
    __syncthreads();
    for (int idx = tid; idx < 512; idx += NT) {
      int oo = idx >> 4, d = idx & 15;
      float S1 = 0.f, S2 = 0.f;
      #pragma unroll
      for (int w2 = 0; w2 < NWAVES; ++w2) { S1 += s1s[w2][oo*17+d]; S2 += s2s[w2][oo*17+d]; }
      float Rs = RsS[oo];
      float m_ = S1 / Rs;
      float sg = (S2 - 2.f*m_*S1 + m_*m_*S0S[oo]) / Rs + EPSR;
      muS[oo*17+d]  = m_;
      isgS[oo*17+d] = 1.f / sg;
      lgS[oo*17+d]  = logf(sg);
    }
    __syncthreads();
    if (tid < 32) {
      float L = 0.f;
      #pragma unroll
      for (int d = 0; d < 16; ++d) L += lgS[tid*17 + d];
      float cost = (16.f*bu[tid] + 0.5f*L) * RsS[tid];
      float av = 1.f / (1.f + expf(-lam * (ba[tid] - cost)));
      aoS[tid] = av;
      laS[tid] = logf(av + EPSR);
      lsS[tid] = 16.f*LOG2PI + L;
    }
    __syncthreads();
    if (p < 2) {
      #pragma unroll
      for (int dd = 0; dd < 8; ++dd) {
        mur[dd]  = muS[o*17 + half*8 + dd];
        isgr[dd] = isgS[o*17 + half*8 + dd];
      }
      lar = laS[o]; lsr = lsS[o];
    }
  }

  if (CONV) {
    int pxo = (bb*Wout + oy)*Wout + ox;
    for (int idx = tid; idx < 512; idx += NT) {
      int oo = idx >> 4, d = idx & 15;
      float val = muS[oo*17 + d];
      float g = bn[oo], be = bn[32+oo], mm = bn[64+oo], vv = bn[96+oo];
      val = (val - mm) * (g * rsqrtf(vv + BNEPS)) + be;
      pose_out[(size_t)pxo*512 + idx] = val;
    }
    if (tid < 32) act_out[(size_t)pxo*32 + tid] = aoS[tid];
  } else {
    for (int idx = tid; idx < 512; idx += NT)
      pose_out[(size_t)bb*512 + idx] = muS[(idx>>4)*17 + (idx&15)];
  }
}

// ---------------- dense caps: per-pass stats + combine ----------------
template<int P>
__global__ __launch_bounds__(256) void dense_stats(
    const float* __restrict__ pose_in, const float* __restrict__ act_in,
    const float* __restrict__ Wv, const float* __restrict__ comb,
    float* __restrict__ stat)
{
  __shared__ float s1s[4][32*17];
  __shared__ float s2s[4][32*17];
  __shared__ float rsP[4][32];
  const int tid = threadIdx.x;
  const int wv = tid >> 6, lane = tid & 63;
  const int o = lane & 31, half = lane >> 5;
  const int bb = blockIdx.x / 12, chunk = blockIdx.x % 12;

  float mur[8], isgr[8], lar = 0.f, lsr = 0.f;
  if (P > 0) {
    const float* cb = comb + (size_t)bb * 1088;
    #pragma unroll
    for (int dd = 0; dd < 8; ++dd) {
      mur[dd]  = cb[o*16 + half*8 + dd];
      isgr[dd] = cb[512 + o*16 + half*8 + dd];
    }
    lar = cb[1024 + o]; lsr = cb[1056 + o];
  }

  float s1r[8] = {0,0,0,0,0,0,0,0};
  float s2r[8] = {0,0,0,0,0,0,0,0};
  float rsr = 0.f;

  for (int it = 0; it < 24; ++it) {
    int n = chunk*96 + wv*24 + it;
    const float* wp = Wv + (size_t)(n*32 + o) * 16;
    float4 w0 = *(const float4*)(wp);
    float4 w1 = *(const float4*)(wp + 4);
    float4 w2 = *(const float4*)(wp + 8);
    float4 w3 = *(const float4*)(wp + 12);
    const float* pp = pose_in + (size_t)(bb*1152 + n) * 16;
    float an = act_in[bb*1152 + n];
    float4 p0 = *(const float4*)(pp + half*8);
    float4 p1 = *(const float4*)(pp + half*8 + 4);
    float v[8];
    v[0] = fmaf(p0.x,w0.x, fmaf(p0.y,w1.x, fmaf(p0.z,w2.x, p0.w*w3.x)));
    v[1] = fmaf(p0.x,w0.y, fmaf(p0.y,w1.y, fmaf(p0.z,w2.y, p0.w*w3.y)));
    v[2] = fmaf(p0.x,w0.z, fmaf(p0.y,w1.z, fmaf(p0.z,w2.z, p0.w*w3.z)));
    v[3] = fmaf(p0.x,w0.w, fmaf(p0.y,w1.w, fmaf(p0.z,w2.w, p0.w*w3.w)));
    v[4] = fmaf(p1.x,w0.x, fmaf(p1.y,w1.x, fmaf(p1.z,w2.x, p1.w*w3.x)));
    v[5] = fmaf(p1.x,w0.y, fmaf(p1.y,w1.y, fmaf(p1.z,w2.y, p1.w*w3.y)));
    v[6] = fmaf(p1.x,w0.z, fmaf(p1.y,w1.z, fmaf(p1.z,w2.z, p1.w*w3.z)));
    v[7] = fmaf(p1.x,w0.w, fmaf(p1.y,w1.w, fmaf(p1.z,w2.w, p1.w*w3.w)));

    float R;
    if (P == 0) {
      R = 1.f / 32.f;
    } else {
      float t = 0.f;
      #pragma unroll
      for (int dd = 0; dd < 8; ++dd) { float df = v[dd] - mur[dd]; t = fmaf(df*df, isgr[dd], t); }
      t += __shfl_xor(t, 32, 64);
      float logit = lar - 0.5f * (t + lsr);
      float mx = logit;
      mx = fmaxf(mx, __shfl_xor(mx, 16, 64));
      mx = fmaxf(mx, __shfl_xor(mx,  8, 64));
      mx = fmaxf(mx, __shfl_xor(mx,  4, 64));
      mx = fmaxf(mx, __shfl_xor(mx,  2, 64));
      mx = fmaxf(mx, __shfl_xor(mx,  1, 64));
      float e = expf(logit - mx);
      float se = e;
      se += __shfl_xor(se, 16, 64);
      se += __shfl_xor(se,  8, 64);
      se += __shfl_xor(se,  4, 64);
      se += __shfl_xor(se,  2, 64);
      se += __shfl_xor(se,  1, 64);
      R = e / se;
    }
    float Ra = R * an;
    rsr += Ra;
    #pragma unroll
    for (int dd = 0; dd < 8; ++dd) {
      s1r[dd] = fmaf(Ra, v[dd], s1r[dd]);
      s2r[dd] = fmaf(Ra * v[dd], v[dd], s2r[dd]);
    }
  }

  #pragma unroll
  for (int dd = 0; dd < 8; ++dd) {
    s1s[wv][o*17 + half*8 + dd] = s1r[dd];
    s2s[wv][o*17 + half*8 + dd] = s2r[dd];
  }
  if (!half) rsP[wv][o] = rsr;
  __syncthreads();

  float* out = stat + (size_t)(bb*12 + chunk) * 1056;
  for (int idx = tid; idx < 512; idx += 256) {
    int oo = idx >> 4, d = idx & 15;
    float S1 = 0.f, S2 = 0.f;
    #pragma unroll
    for (int w2 = 0; w2 < 4; ++w2) { S1 += s1s[w2][oo*17+d]; S2 += s2s[w2][oo*17+d]; }
    out[idx] = S1; out[512 + idx] = S2;
  }
  if (tid < 32) {
    float r = 0.f;
    #pragma unroll
    for (int w2 = 0; w2 < 4; ++w2) r += rsP[w2][tid];
    out[1024 + tid] = r;
  }
}

template<int P>
__global__ __launch_bounds__(256) void dense_comb(
    const float* __restrict__ stat,
    const float* __restrict__ ba, const float* __restrict__ bu,
    float* __restrict__ comb, float* __restrict__ decin)
{
  __shared__ float S0S[32], RsS[32], lgS[32*17];
  const int tid = threadIdx.x;
  const int bb = blockIdx.x;
  const float* st = stat + (size_t)bb * 12 * 1056;
  float* cb = comb + (size_t)bb * 1088;

  if (tid < 32) {
    float r = 0.f;
    #pragma unroll
    for (int c = 0; c < 12; ++c) r += st[c*1056 + 1024 + tid];
    S0S[tid] = r; RsS[tid] = r + EPSR;
  }
  __syncthreads();
  for (int idx = tid; idx < 512; idx += 256) {
    int oo = idx >> 4, d = idx & 15;
    float S1 = 0.f, S2 = 0.f;
    #pragma unroll
    for (int c = 0; c < 12; ++c) { S1 += st[c*1056 + idx]; S2 += st[c*1056 + 512 + idx]; }
    float Rs = RsS[oo];
    float m_ = S1 / Rs;
    float sg = (S2 - 2.f*m_*S1 + m_*m_*S0S[oo]) / Rs + EPSR;
    if (P == 2) {
      decin[(size_t)bb*512 + idx] = m_;
    } else {
      cb[idx] = m_;
      cb[512 + idx] = 1.f / sg;
    }
    lgS[oo*17 + d] = logf(sg);
  }
  __syncthreads();
  if (P < 2 && tid < 32) {
    float L = 0.f;
    #pragma unroll
    for (int d = 0; d < 16; ++d) L += lgS[tid*17 + d];
    float lam = 0.01f * (float)(P + 1);
    float cost = (16.f*bu[tid] + 0.5f*L) * RsS[tid];
    float av = 1.f / (1.f + expf(-lam * (ba[tid] - cost)));
    cb[1024 + tid] = logf(av + EPSR);
    cb[1056 + tid] = 16.f*LOG2PI + L;
  }
}

// ---------------- decoder FC: K-split partial + reduce ----------------
__global__ __launch_bounds__(256) void fc_partial(
    const float* __restrict__ in, const float* __restrict__ W,
    float* __restrict__ part, int K, int N, int CK)
{
  int t = blockIdx.x * 256 + threadIdx.x;
  int nj = N >> 2;
  int j4 = t % nj, ks = t / nj;
  int k0 = ks * CK;
  float4 a0 = make_float4(0,0,0,0), a1 = make_float4(0,0,0,0);
  const float4* Wp = (const float4*)W;
  for (int kk = 0; kk < CK; ++kk) {
    int k = k0 + kk;
    float4 wv = Wp[(size_t)k * nj + j4];
    float f0 = in[k], f1 = in[K + k];
    a0.x = fmaf(f0, wv.x, a0.x); a0.y = fmaf(f0, wv.y, a0.y);
    a0.z = fmaf(f0, wv.z, a0.z); a0.w = fmaf(f0, wv.w, a0.w);
    a1.x = fmaf(f1, wv.x, a1.x); a1.y = fmaf(f1, wv.y, a1.y);
    a1.z = fmaf(f1, wv.z, a1.z); a1.w = fmaf(f1, wv.w, a1.w);
  }
  ((float4*)part)[(size_t)(ks*2 + 0) * nj + j4] = a0;
  ((float4*)part)[(size_t)(ks*2 + 1) * nj + j4] = a1;
}

__global__ __launch_bounds__(256) void fc_reduce(
    const float* __restrict__ part, const float* __restrict__ bias,
    float* __restrict__ out, int N, int KS, int relu)
{
  int t = blockIdx.x * 256 + threadIdx.x;
  int b = t / N, j = t - b*N;
  float s = bias[j];
  for (int ks = 0; ks < KS; ++ks) s += part[(size_t)(ks*2 + b) * N + j];
  if (relu) s = fmaxf(s, 0.f);
  out[(size_t)b*N + j] = s;
}

// ---------------- launch ----------------
extern "C" void kernel_launch(void* const* d_in, const int* in_sizes, int n_in,
                              void* d_out, int out_size, void* d_ws, size_t ws_size,
                              hipStream_t stream) {
  const float* x    = (const float*)d_in[0];
  const float* c1w  = (const float*)d_in[1];
  const float* c1b  = (const float*)d_in[2];
  const float* bn1  = (const float*)d_in[3];
  const float* ppw  = (const float*)d_in[4];
  const float* ppb  = (const float*)d_in[5];
  const float* paw  = (const float*)d_in[6];
  const float* pab  = (const float*)d_in[7];
  const float* bn2  = (const float*)d_in[8];
  const float* ccw1 = (const float*)d_in[9];
  const float* cba1 = (const float*)d_in[10];
  const float* cbu1 = (const float*)d_in[11];
  const float* bn3  = (const float*)d_in[12];
  const float* ccw2 = (const float*)d_in[13];
  const float* cba2 = (const float*)d_in[14];
  const float* cbu2 = (const float*)d_in[15];
  const float* bn4  = (const float*)d_in[16];
  const float* dcw  = (const float*)d_in[17];
  const float* dcba = (const float*)d_in[18];
  const float* dcbu = (const float*)d_in[19];
  const float* w1   = (const float*)d_in[20];
  const float* b1   = (const float*)d_in[21];
  const float* w2   = (const float*)d_in[22];
  const float* b2   = (const float*)d_in[23];
  const float* w3   = (const float*)d_in[24];
  const float* b3   = (const float*)d_in[25];

  float* ws    = (float*)d_ws;
  float* h     = ws + O_H;
  f16*   hh    = (f16*)(ws + O_H);
  f16*   hl    = hh + 786432;
  float* pose2 = ws + O_POSE2;
  float* act2  = ws + O_ACT2;
  float* pose3 = ws + O_POSE3;
  float* act3  = ws + O_ACT3;
  float* pose4 = ws + O_POSE4;
  float* act4  = ws + O_ACT4;
  float* decin = ws + O_DECIN;
  float* h1    = ws + O_H1;
  float* h2    = ws + O_H2;
  float* part  = ws + O_PART;
  f16*   bwh   = (f16*)(ws + O_BWH);
  f16*   bwl   = (f16*)(ws + O_BWL);
  float* dstat = ws + O_DSTAT;
  float* dcomb = ws + O_DCOMB;

  const bool fast = ws_size >= NEED_BYTES;

  if (fast) {
    conv1_k<1><<<3072, 256, 0, stream>>>(x, c1w, c1b, bn1, nullptr, hh, hl);
    split_w_k<<<dim3(243, 20), 256, 0, stream>>>(ppw, paw, bwh, bwl);
    zero_raw<<<3332, 256, 0, stream>>>(pose2, act2);
    conv2_mfma<<<dim3(13, 5, 8), 256, 0, stream>>>(hh, hl, bwh, bwl, pose2, act2);
  } else {
    conv1_k<0><<<3072, 256, 0, stream>>>(x, c1w, c1b, bn1, h, nullptr, nullptr);
    zero_raw<<<3332, 256, 0, stream>>>(pose2, act2);
    conv2_gemm_ks<<<dim3(25, 9, 6), 256, 0, stream>>>(h, ppw, paw, pose2, act2);
  }
  conv2_epi<<<3332, 256, 0, stream>>>(ppb, pab, bn2, pose2, act2);
  routing_k<288, 8, true><<<338, 512, 0, stream>>>(pose2, act2, ccw1, cba1, cbu1, bn3,
                                                   pose3, act3, 28, 28, 13);
  routing_k<288, 8, true><<<72, 512, 0, stream>>>(pose3, act3, ccw2, cba2, cbu2, bn4,
                                                  pose4, act4, 13, 13, 6);
  dense_stats<0><<<24, 256, 0, stream>>>(pose4, act4, dcw, nullptr, dstat);
  dense_comb<0><<<2, 256, 0, stream>>>(dstat, dcba, dcbu, dcomb, nullptr);
  dense_stats<1><<<24, 256, 0, stream>>>(pose4, act4, dcw, dcomb, dstat);
  dense_comb<1><<<2, 256, 0, stream>>>(dstat, dcba, dcbu, dcomb, nullptr);
  dense_stats<2><<<24, 256, 0, stream>>>(pose4, act4, dcw, dcomb, dstat);
  dense_comb<2><<<2, 256, 0, stream>>>(dstat, dcba, dcbu, dcomb, decin);
  fc_partial<<<8, 256, 0, stream>>>(decin, w1, part, 512, 512, 32);
  fc_reduce<<<4, 256, 0, stream>>>(part, b1, h1, 512, 16, 1);
  fc_partial<<<16, 256, 0, stream>>>(h1, w2, part, 512, 1024, 32);
  fc_reduce<<<8, 256, 0, stream>>>(part, b2, h2, 1024, 16, 1);
  fc_partial<<<64, 256, 0, stream>>>(h2, w3, part, 1024, 8192, 128);
  fc_reduce<<<64, 256, 0, stream>>>(part, b3, (float*)d_out, 8192, 8, 0);
}

// Round 6
// 679.517 us; speedup vs baseline: 1.8938x; 1.0253x over previous
//
#include <hip/hip_runtime.h>
#include <hip/hip_bf16.h>

#define EPSR 1e-8f
#define BNEPS 1e-3f
#define LOG2PI 1.8378770664093453f

typedef _Float16 f16;
typedef _Float16 f16x4 __attribute__((ext_vector_type(4)));
typedef _Float16 f16x8 __attribute__((ext_vector_type(8)));
typedef float f32x4 __attribute__((ext_vector_type(4)));

// ---------------- ws layout (float offsets) ----------------
#define O_H      0          // fast: h_hi/h_lo f16 (2*786432 f16); fallback: h fp32 786432
#define O_POSE2  786432     // pose2: 2*28*28*512  = 802816
#define O_ACT2   1589248    // act2:  2*28*28*32   = 50176
#define O_POSE3  1639424    // pose3: 2*13*13*512  = 173056
#define O_ACT3   1812480    // act3:  2*13*13*32   = 10816
#define O_POSE4  1823296    // pose4: 2*6*6*512    = 36864
#define O_ACT4   1860160    // act4:  2*6*6*32     = 2304
#define O_DECIN  1862464    // 2*512
#define O_H1     1863488    // 2*512
#define O_H2     1864512    // 2*1024
#define O_PART   1866560    // fc3 KS=32: 32*2*8192 = 524288 -> ends 2390848 (overlaps dead bwh region; ok post-conv2)
#define O_BWH    1997632    // Bw_hi f16 [640][7776] = 2488320 floats (dead after conv2_mfma)
#define O_BWL    4485952    // Bw_lo  -> ends 6974272 floats
#define NEED_BYTES (6974272ull * 4ull)
// dense routing scratch reuses O_H (dead after conv2):
#define O_DSTAT  0          // 24 * 1056 floats
#define O_DCOMB  32768      // 2 * 1088 floats

// ---------------- conv1: 11x11 s2 SAME 3->96 + bias + relu + BN1 ----------------
template<int F16>
__global__ __launch_bounds__(256) void conv1_k(
    const float* __restrict__ x, const float* __restrict__ w,
    const float* __restrict__ bias, const float* __restrict__ bn1,
    float* __restrict__ h32, f16* __restrict__ hh, f16* __restrict__ hl)
{
  int t = blockIdx.x * 256 + threadIdx.x;        // 786432 total
  int c = t % 96; int px = t / 96;
  int ox = px & 63; int r = px >> 6; int oy = r & 63; int b = r >> 6;
  float acc = 0.f;
  int iy0 = 2*oy - 4, ix0 = 2*ox - 4;
  for (int ky = 0; ky < 11; ++ky) {
    int iy = iy0 + ky;
    if ((unsigned)iy > 127u) continue;
    const float* xrow = x + (size_t)((b*128 + iy)*128)*3;
    const float* wrow = w + (ky*11*3)*96 + c;
    for (int kx = 0; kx < 11; ++kx) {
      int ix = ix0 + kx;
      if ((unsigned)ix > 127u) continue;
      const float* xp = xrow + ix*3;
      const float* wp = wrow + kx*3*96;
      acc = fmaf(xp[0], wp[0],   acc);
      acc = fmaf(xp[1], wp[96],  acc);
      acc = fmaf(xp[2], wp[192], acc);
    }
  }
  acc += bias[c];
  acc = fmaxf(acc, 0.f);
  float g = bn1[c], be = bn1[96+c], mm = bn1[192+c], vv = bn1[288+c];
  float val = (acc - mm) * (g * rsqrtf(vv + BNEPS)) + be;
  if (F16) {
    f16 hi = (f16)val;
    f16 lo = (f16)(val - (float)hi);
    hh[t] = hi; hl[t] = lo;
  } else {
    h32[t] = val;
  }
}

// ---------------- weight transpose + f16 split: Bw[640][7776] hi/lo ----------------
__global__ __launch_bounds__(256) void split_w_k(
    const float* __restrict__ pw, const float* __restrict__ aw,
    f16* __restrict__ bwh, f16* __restrict__ bwl)
{
  __shared__ float tile[32][33];
  const int kb = blockIdx.x * 32, nb = blockIdx.y * 32;
  const int t = threadIdx.x;
  #pragma unroll
  for (int p = 0; p < 4; ++p) {
    int k_l = p*8 + (t>>5), n_l = t & 31;
    int k = kb + k_l, n = nb + n_l;
    float v = 0.f;
    if (n < 512) v = pw[(size_t)k*512 + n];
    else if (n < 544) v = aw[(size_t)k*32 + (n - 512)];
    tile[k_l][n_l] = v;
  }
  __syncthreads();
  #pragma unroll
  for (int p = 0; p < 4; ++p) {
    int n_l = p*8 + (t>>5), k_l = t & 31;
    float v = tile[k_l][n_l];
    f16 hi = (f16)v;
    f16 lo = (f16)(v - (float)hi);
    size_t dst = (size_t)(nb + n_l)*7776 + kb + k_l;
    bwh[dst] = hi; bwl[dst] = lo;
  }
}

// ---------------- zero raw accumulators ----------------
__global__ __launch_bounds__(256) void zero_raw(float* __restrict__ pose2, float* __restrict__ act2)
{
  int t = blockIdx.x * 256 + threadIdx.x;   // 852992 total
  if (t < 802816) pose2[t] = 0.f;
  else act2[t - 802816] = 0.f;
}

// ---------------- conv2 as fp16-split (3-MFMA) GEMM ----------------
__global__ __launch_bounds__(256, 2) void conv2_mfma(
    const f16* __restrict__ hh, const f16* __restrict__ hl,
    const f16* __restrict__ bwh, const f16* __restrict__ bwl,
    float* __restrict__ pose2r, float* __restrict__ act2r)
{
  __shared__ f16 Ah[128*32];
  __shared__ f16 Al[128*32];
  __shared__ f16 Bh[128*32];
  __shared__ f16 Bl[128*32];
  const int tid = threadIdx.x;
  const int mb = blockIdx.x, nb = blockIdx.y, z = blockIdx.z;
  const int m0 = mb*128, n0 = nb*128;
  const int q = 243 / 8, rch = 243 % 8;
  const int k0 = z*q + (z < rch ? z : rch);
  const int k1 = k0 + q + (z < rch ? 1 : 0);

  const int srow = tid >> 3;
  const int c    = tid & 7;
  int habase[4]; bool amok[4];
  #pragma unroll
  for (int p = 0; p < 4; ++p) {
    int m = m0 + p*32 + srow;
    amok[p] = m < 1568;
    int mm = amok[p] ? m : 0;
    int b = mm / 784; int yx = mm - b*784; int oy = yx / 28, ox = yx - oy*28;
    habase[p] = ((b*64 + 2*oy)*64 + 2*ox)*96;
  }
  size_t bbase[4];
  #pragma unroll
  for (int p = 0; p < 4; ++p) bbase[p] = (size_t)(n0 + p*32 + srow) * 7776;

  f16x4 rah[4], ral[4], rbh[4], rbl[4];
  const f16x4 zv = {(f16)0, (f16)0, (f16)0, (f16)0};

  auto load_step = [&](int kt) {
    int ky = kt / 27, rr = kt % 27; int kx = rr / 3, ci0 = (rr % 3) * 32;
    int aoff = (ky*64 + kx)*96 + ci0 + c*4;
    int koff = kt*32 + c*4;
    #pragma unroll
    for (int p = 0; p < 4; ++p) {
      if (amok[p]) {
        rah[p] = *(const f16x4*)(hh + habase[p] + aoff);
        ral[p] = *(const f16x4*)(hl + habase[p] + aoff);
      } else { rah[p] = zv; ral[p] = zv; }
      rbh[p] = *(const f16x4*)(bwh + bbase[p] + koff);
      rbl[p] = *(const f16x4*)(bwl + bbase[p] + koff);
    }
  };

  int widx[4];
  #pragma unroll
  for (int p = 0; p < 4; ++p) {
    int row = p*32 + srow;
    widx[p] = row*32 + ((((c>>1) + (row>>1)) & 3) << 3) + ((c & 1) << 2);
  }

  const int wv = tid >> 6, lane = tid & 63;
  const int wr = wv >> 1, wc = wv & 1;
  const int l15 = lane & 15, g = lane >> 4;

  f32x4 acc[4][4];
  #pragma unroll
  for (int i = 0; i < 4; ++i)
    #pragma unroll
    for (int j = 0; j < 4; ++j) acc[i][j] = (f32x4){0.f, 0.f, 0.f, 0.f};

  int aidx[4], bidx[4];
  #pragma unroll
  for (int i = 0; i < 4; ++i) {
    int arow = wr*64 + i*16 + l15;
    aidx[i] = arow*32 + (((g + (arow>>1)) & 3) << 3);
    int brow = wc*64 + i*16 + l15;
    bidx[i] = brow*32 + (((g + (brow>>1)) & 3) << 3);
  }

  load_step(k0);
  for (int kt = k0; kt < k1; ++kt) {
    __syncthreads();
    #pragma unroll
    for (int p = 0; p < 4; ++p) {
      *(f16x4*)&Ah[widx[p]] = rah[p];
      *(f16x4*)&Al[widx[p]] = ral[p];
      *(f16x4*)&Bh[widx[p]] = rbh[p];
      *(f16x4*)&Bl[widx[p]] = rbl[p];
    }
    __syncthreads();
    if (kt + 1 < k1) load_step(kt + 1);
    f16x8 ah[4], al[4], bh[4], bl[4];
    #pragma unroll
    for (int i = 0; i < 4; ++i) {
      ah[i] = *(const f16x8*)&Ah[aidx[i]];
      al[i] = *(const f16x8*)&Al[aidx[i]];
      bh[i] = *(const f16x8*)&Bh[bidx[i]];
      bl[i] = *(const f16x8*)&Bl[bidx[i]];
    }
    #pragma unroll
    for (int i = 0; i < 4; ++i)
      #pragma unroll
      for (int j = 0; j < 4; ++j) {
        acc[i][j] = __builtin_amdgcn_mfma_f32_16x16x32_f16(ah[i], bh[j], acc[i][j], 0, 0, 0);
        acc[i][j] = __builtin_amdgcn_mfma_f32_16x16x32_f16(ah[i], bl[j], acc[i][j], 0, 0, 0);
        acc[i][j] = __builtin_amdgcn_mfma_f32_16x16x32_f16(al[i], bh[j], acc[i][j], 0, 0, 0);
      }
  }

  #pragma unroll
  for (int i = 0; i < 4; ++i) {
    #pragma unroll
    for (int j = 0; j < 4; ++j) {
      #pragma unroll
      for (int r2 = 0; r2 < 4; ++r2) {
        int m = m0 + wr*64 + i*16 + g*4 + r2;
        int n = n0 + wc*64 + j*16 + l15;
        if (m < 1568) {
          float val = acc[i][j][r2];
          if (n < 512) atomicAdd(&pose2r[(size_t)m*512 + n], val);
          else if (n < 544) atomicAdd(&act2r[(size_t)m*32 + (n - 512)], val);
        }
      }
    }
  }
}

// ---------------- fallback fp32 conv2 ----------------
__global__ __launch_bounds__(256) void conv2_gemm_ks(
    const float* __restrict__ h,
    const float* __restrict__ pw, const float* __restrict__ aw,
    float* __restrict__ pose2r, float* __restrict__ act2r)
{
  __shared__ float As[2][16][68];
  __shared__ float Bs[2][16][68];
  const int tid = threadIdx.x;
  const int mb = blockIdx.x, nb = blockIdx.y, z = blockIdx.z;
  const int m0 = mb * 64;
  const float* Bp; int ldB, n0;
  if (nb < 8) { Bp = pw; ldB = 512; n0 = nb * 64; } else { Bp = aw; ldB = 32; n0 = 0; }

  const int a_ml = tid & 63, a_cig = tid >> 6;
  const int am = m0 + a_ml;
  const bool am_ok = am < 1568;
  int ab_ = am / 784; int ayx = am - ab_*784;
  int aoy = ayx / 28, aox = ayx - aoy*28;
  if (!am_ok) { ab_ = 0; aoy = 0; aox = 0; }
  const float* a_base = h + (size_t)((ab_*64 + 2*aoy)*64 + 2*aox)*96 + a_cig*4;

  const int b_kk = tid >> 4, b_ng = tid & 15;
  const int b_col = b_ng * 4;
  const bool b_ok = b_col < ldB;

  const int tm = (tid & 15) * 4, tn = (tid >> 4) * 4;
  float acc[4][4] = {{0}};

  auto kidx = [](int kt, int& ky, int& kx, int& ci0) {
    int cig = kt % 6; int r = kt / 6; kx = r % 9; ky = r / 9; ci0 = cig * 16;
  };
  auto ldAv = [&](int ky, int kx, int ci0) -> float4 {
    if (!am_ok) return make_float4(0,0,0,0);
    return *(const float4*)(a_base + (ky*64 + kx)*96 + ci0);
  };
  auto ldBv = [&](int kt) -> float4 {
    if (!b_ok) return make_float4(0,0,0,0);
    return *(const float4*)(Bp + (size_t)(kt*16 + b_kk) * ldB + n0 + b_col);
  };
  auto wrAv = [&](float4 v, int buf) {
    As[buf][a_cig*4+0][a_ml] = v.x;
    As[buf][a_cig*4+1][a_ml] = v.y;
    As[buf][a_cig*4+2][a_ml] = v.z;
    As[buf][a_cig*4+3][a_ml] = v.w;
  };
  auto wrBv = [&](float4 v, int buf) {
    *(float4*)&Bs[buf][b_kk][b_col] = v;
  };

  const int kt0 = z * 81;
  {
    int ky, kx, ci0; kidx(kt0, ky, kx, ci0);
    wrAv(ldAv(ky, kx, ci0), 0); wrBv(ldBv(kt0), 0);
  }
  __syncthreads();

  for (int i = 0; i < 81; ++i) {
    int cur = i & 1;
    bool st = i < 80;
    float4 va, vb;
    if (st) {
      int ky, kx, ci0; kidx(kt0 + i + 1, ky, kx, ci0);
      va = ldAv(ky, kx, ci0);
      vb = ldBv(kt0 + i + 1);
    }
    #pragma unroll
    for (int kk = 0; kk < 16; ++kk) {
      float4 av = *(const float4*)&As[cur][kk][tm];
      float4 bv = *(const float4*)&Bs[cur][kk][tn];
      float aa[4] = {av.x, av.y, av.z, av.w};
      float bb4[4] = {bv.x, bv.y, bv.z, bv.w};
      #pragma unroll
      for (int ii = 0; ii < 4; ++ii)
        #pragma unroll
        for (int jj = 0; jj < 4; ++jj)
          acc[ii][jj] = fmaf(aa[ii], bb4[jj], acc[ii][jj]);
    }
    if (st) { wrAv(va, cur ^ 1); wrBv(vb, cur ^ 1); }
    __syncthreads();
  }

  #pragma unroll
  for (int i = 0; i < 4; ++i) {
    int m = m0 + tm + i;
    if (m >= 1568) break;
    #pragma unroll
    for (int j = 0; j < 4; ++j) {
      int nl = tn + j;
      if (nb < 8) {
        atomicAdd(&pose2r[(size_t)m*512 + n0 + nl], acc[i][j]);
      } else if (nl < 32) {
        atomicAdd(&act2r[(size_t)m*32 + nl], acc[i][j]);
      }
    }
  }
}

// ---------------- conv2 epilogue ----------------
__global__ __launch_bounds__(256) void conv2_epi(
    const float* __restrict__ pb, const float* __restrict__ ab,
    const float* __restrict__ bn2,
    float* __restrict__ pose2, float* __restrict__ act2)
{
  int t = blockIdx.x * 256 + threadIdx.x;   // 852992 total
  if (t < 802816) {
    int n = t & 511;
    float val = pose2[t] + pb[n];
    int caps = n >> 4;
    float g = bn2[caps], be = bn2[32+caps], mm = bn2[64+caps], vv = bn2[96+caps];
    pose2[t] = (val - mm) * (g * rsqrtf(vv + BNEPS)) + be;
  } else {
    int t2 = t - 802816;
    int nl = t2 & 31;
    float val = act2[t2] + ab[nl];
    act2[t2] = 1.f / (1.f + expf(-val));
  }
}

// ---------------- fused votes + EM routing (conv caps), register-prefetched ----------------
template<int NIN, int NWAVES, bool CONV>
__global__ __launch_bounds__(NWAVES*64) void routing_k(
    const float* __restrict__ pose_in, const float* __restrict__ act_in,
    const float* __restrict__ Wv,
    const float* __restrict__ ba, const float* __restrict__ bu,
    const float* __restrict__ bn,
    float* __restrict__ pose_out, float* __restrict__ act_out,
    int Hin, int Win, int Wout)
{
  constexpr int NT  = NWAVES * 64;
  constexpr int NPW = NIN / NWAVES;
  __shared__ float s1s[NWAVES][32*17];
  __shared__ float s2s[NWAVES][32*17];
  __shared__ float rsP[NWAVES][32];
  __shared__ float muS[32*17], isgS[32*17], lgS[32*17];
  __shared__ float laS[32], lsS[32], aoS[32], RsS[32], S0S[32];

  const int tid = threadIdx.x;
  const int wv = tid >> 6, lane = tid & 63;
  const int o = lane & 31, half = lane >> 5;

  int bb = 0, oy = 0, ox = 0;
  if (CONV) {
    int px = blockIdx.x;
    ox = px % Wout; int t2 = px / Wout; oy = t2 % Wout; bb = t2 / Wout;
  } else {
    bb = blockIdx.x;
  }

  // prefetch loader: W fragment + pose pair + act for input capsule n
  auto ld_n = [&](int n, float4& W0, float4& W1, float4& W2, float4& W3,
                  float4& P0, float4& P1, float& AN) {
    const float* wp = Wv + (size_t)(n*32 + o) * 16;
    W0 = *(const float4*)(wp);
    W1 = *(const float4*)(wp + 4);
    W2 = *(const float4*)(wp + 8);
    W3 = *(const float4*)(wp + 12);
    const float* pp;
    if (CONV) {
      int cc = n & 31, kk = n >> 5;
      int ki = kk / 3, kj = kk - ki*3;
      int pix = (bb*Hin + 2*oy + ki)*Win + 2*ox + kj;
      pp = pose_in + (size_t)(pix*32 + cc) * 16;
      AN = act_in[pix*32 + cc];
    } else {
      pp = pose_in + (size_t)(bb*NIN + n) * 16;
      AN = act_in[bb*NIN + n];
    }
    P0 = *(const float4*)(pp + half*8);
    P1 = *(const float4*)(pp + half*8 + 4);
  };

  float mur[8], isgr[8], lar = 0.f, lsr = 0.f;
  #pragma unroll
  for (int i = 0; i < 8; ++i) { mur[i] = 0.f; isgr[i] = 0.f; }

  for (int p = 0; p < 3; ++p) {
    float lam = 0.01f * (float)(p + 1);
    float s1r[8] = {0,0,0,0,0,0,0,0};
    float s2r[8] = {0,0,0,0,0,0,0,0};
    float rsr = 0.f;

    float4 w0, w1, w2, w3, p0, p1; float an;
    ld_n(wv*NPW, w0, w1, w2, w3, p0, p1, an);

    for (int it = 0; it < NPW; ++it) {
      // snapshot current, issue next-iteration loads (hide L2 latency under softmax chain)
      float4 cw0=w0, cw1=w1, cw2=w2, cw3=w3, cp0=p0, cp1=p1; float can=an;
      if (it + 1 < NPW) ld_n(wv*NPW + it + 1, w0, w1, w2, w3, p0, p1, an);

      float v[8];
      v[0] = fmaf(cp0.x,cw0.x, fmaf(cp0.y,cw1.x, fmaf(cp0.z,cw2.x, cp0.w*cw3.x)));
      v[1] = fmaf(cp0.x,cw0.y, fmaf(cp0.y,cw1.y, fmaf(cp0.z,cw2.y, cp0.w*cw3.y)));
      v[2] = fmaf(cp0.x,cw0.z, fmaf(cp0.y,cw1.z, fmaf(cp0.z,cw2.z, cp0.w*cw3.z)));
      v[3] = fmaf(cp0.x,cw0.w, fmaf(cp0.y,cw1.w, fmaf(cp0.z,cw2.w, cp0.w*cw3.w)));
      v[4] = fmaf(cp1.x,cw0.x, fmaf(cp1.y,cw1.x, fmaf(cp1.z,cw2.x, cp1.w*cw3.x)));
      v[5] = fmaf(cp1.x,cw0.y, fmaf(cp1.y,cw1.y, fmaf(cp1.z,cw2.y, cp1.w*cw3.y)));
      v[6] = fmaf(cp1.x,cw0.z, fmaf(cp1.y,cw1.z, fmaf(cp1.z,cw2.z, cp1.w*cw3.z)));
      v[7] = fmaf(cp1.x,cw0.w, fmaf(cp1.y,cw1.w, fmaf(cp1.z,cw2.w, cp1.w*cw3.w)));

      float R;
      if (p == 0) {
        R = 1.f / 32.f;
      } else {
        float t = 0.f;
        #pragma unroll
        for (int dd = 0; dd < 8; ++dd) { float df = v[dd] - mur[dd]; t = fmaf(df*df, isgr[dd], t); }
        t += __shfl_xor(t, 32, 64);
        float logit = lar - 0.5f * (t + lsr);
        float mx = logit;
        mx = fmaxf(mx, __shfl_xor(mx, 16, 64));
        mx = fmaxf(mx, __shfl_xor(mx,  8, 64));
        mx = fmaxf(mx, __shfl_xor(mx,  4, 64));
        mx = fmaxf(mx, __shfl_xor(mx,  2, 64));
        mx = fmaxf(mx, __shfl_xor(mx,  1, 64));
        float e = expf(logit - mx);
        float se = e;
        se += __shfl_xor(se, 16, 64);
        se += __shfl_xor(se,  8, 64);
        se += __shfl_xor(se,  4, 64);
        se += __shfl_xor(se,  2, 64);
        se += __shfl_xor(se,  1, 64);
        R = e / se;
      }
      float Ra = R * can;
      rsr += Ra;
      #pragma unroll
      for (int dd = 0; dd < 8; ++dd) {
        s1r[dd] = fmaf(Ra, v[dd], s1r[dd]);
        s2r[dd] = fmaf(Ra * v[dd], v[dd], s2r[dd]);
      }
    }

    #pragma unroll
    for (int dd = 0; dd < 8; ++dd) {
      s1s[wv][o*17 + half*8 + dd] = s1r[dd];
      s2s[wv][o*17 + half*8 + dd] = s2r[dd];
    }
    if (!half) rsP[wv][o] = rsr;
    __syncthreads();
    if (tid < 32) {
      float r = 0.f;
      #pragma unroll
      for (int w2 = 0; w2 < NWAVES; ++w2) r += rsP[w2][tid];
      S0S[tid] = r; RsS[tid] = r + EPSR;
    }
    __syncthreads();
    for (int idx = tid; idx < 512; idx += NT) {
      int oo = idx >> 4, d = idx & 15;
      float S1 = 0.f, S2 = 0.f;
      #pragma unroll
      for (int w2 = 0; w2 < NWAVES; ++w2) { S1 += s1s[w2][oo*17+d]; S2 += s2s[w2][oo*17+d]; }
      float Rs = RsS[oo];
      float m_ = S1 / Rs;
      float sg = (S2 - 2.f*m_*S1 + m_*m_*S0S[oo]) / Rs + EPSR;
      muS[oo*17+d]  = m_;
      isgS[oo*17+d] = 1.f / sg;
      lgS[oo*17+d]  = logf(sg);
    }
    __syncthreads();
    if (tid < 32) {
      float L = 0.f;
      #pragma unroll
      for (int d = 0; d < 16; ++d) L += lgS[tid*17 + d];
      float cost = (16.f*bu[tid] + 0.5f*L) * RsS[tid];
      float av = 1.f / (1.f + expf(-lam * (ba[tid] - cost)));
      aoS[tid] = av;
      laS[tid] = logf(av + EPSR);
      lsS[tid] = 16.f*LOG2PI + L;
    }
    __syncthreads();
    if (p < 2) {
      #pragma unroll
      for (int dd = 0; dd < 8; ++dd) {
        mur[dd]  = muS[o*17 + half*8 + dd];
        isgr[dd] = isgS[o*17 + half*8 + dd];
      }
      lar = laS[o]; lsr = lsS[o];
    }
  }

  if (CONV) {
    int pxo = (bb*Wout + oy)*Wout + ox;
    for (int idx = tid; idx < 512; idx += NT) {
      int oo = idx >> 4, d = idx & 15;
      float val = muS[oo*17 + d];
      float g = bn[oo], be = bn[32+oo], mm = bn[64+oo], vv = bn[96+oo];
      val = (val - mm) * (g * rsqrtf(vv + BNEPS)) + be;
      pose_out[(size_t)pxo*512 + idx] = val;
    }
    if (tid < 32) act_out[(size_t)pxo*32 + tid] = aoS[tid];
  } else {
    for (int idx = tid; idx < 512; idx += NT)
      pose_out[(size_t)bb*512 + idx] = muS[(idx>>4)*17 + (idx&15)];
  }
}

// ---------------- dense caps: per-pass stats + combine (prefetched) ----------------
template<int P>
__global__ __launch_bounds__(256) void dense_stats(
    const float* __restrict__ pose_in, const float* __restrict__ act_in,
    const float* __restrict__ Wv, const float* __restrict__ comb,
    float* __restrict__ stat)
{
  __shared__ float s1s[4][32*17];
  __shared__ float s2s[4][32*17];
  __shared__ float rsP[4][32];
  const int tid = threadIdx.x;
  const int wv = tid >> 6, lane = tid & 63;
  const int o = lane & 31, half = lane >> 5;
  const int bb = blockIdx.x / 12, chunk = blockIdx.x % 12;

  float mur[8], isgr[8], lar = 0.f, lsr = 0.f;
  if (P > 0) {
    const float* cb = comb + (size_t)bb * 1088;
    #pragma unroll
    for (int dd = 0; dd < 8; ++dd) {
      mur[dd]  = cb[o*16 + half*8 + dd];
      isgr[dd] = cb[512 + o*16 + half*8 + dd];
    }
    lar = cb[1024 + o]; lsr = cb[1056 + o];
  }

  auto ld_n = [&](int n, float4& W0, float4& W1, float4& W2, float4& W3,
                  float4& P0, float4& P1, float& AN) {
    const float* wp = Wv + (size_t)(n*32 + o) * 16;
    W0 = *(const float4*)(wp);
    W1 = *(const float4*)(wp + 4);
    W2 = *(const float4*)(wp + 8);
    W3 = *(const float4*)(wp + 12);
    const float* pp = pose_in + (size_t)(bb*1152 + n) * 16;
    AN = act_in[bb*1152 + n];
    P0 = *(const float4*)(pp + half*8);
    P1 = *(const float4*)(pp + half*8 + 4);
  };

  float s1r[8] = {0,0,0,0,0,0,0,0};
  float s2r[8] = {0,0,0,0,0,0,0,0};
  float rsr = 0.f;

  float4 w0, w1, w2, w3, p0, p1; float an;
  ld_n(chunk*96 + wv*24, w0, w1, w2, w3, p0, p1, an);

  for (int it = 0; it < 24; ++it) {
    float4 cw0=w0, cw1=w1, cw2=w2, cw3=w3, cp0=p0, cp1=p1; float can=an;
    if (it + 1 < 24) ld_n(chunk*96 + wv*24 + it + 1, w0, w1, w2, w3, p0, p1, an);

    float v[8];
    v[0] = fmaf(cp0.x,cw0.x, fmaf(cp0.y,cw1.x, fmaf(cp0.z,cw2.x, cp0.w*cw3.x)));
    v[1] = fmaf(cp0.x,cw0.y, fmaf(cp0.y,cw1.y, fmaf(cp0.z,cw2.y, cp0.w*cw3.y)));
    v[2] = fmaf(cp0.x,cw0.z, fmaf(cp0.y,cw1.z, fmaf(cp0.z,cw2.z, cp0.w*cw3.z)));
    v[3] = fmaf(cp0.x,cw0.w, fmaf(cp0.y,cw1.w, fmaf(cp0.z,cw2.w, cp0.w*cw3.w)));
    v[4] = fmaf(cp1.x,cw0.x, fmaf(cp1.y,cw1.x, fmaf(cp1.z,cw2.x, cp1.w*cw3.x)));
    v[5] = fmaf(cp1.x,cw0.y, fmaf(cp1.y,cw1.y, fmaf(cp1.z,cw2.y, cp1.w*cw3.y)));
    v[6] = fmaf(cp1.x,cw0.z, fmaf(cp1.y,cw1.z, fmaf(cp1.z,cw2.z, cp1.w*cw3.z)));
    v[7] = fmaf(cp1.x,cw0.w, fmaf(cp1.y,cw1.w, fmaf(cp1.z,cw2.w, cp1.w*cw3.w)));

    float R;
    if (P == 0) {
      R = 1.f / 32.f;
    } else {
      float t = 0.f;
      #pragma unroll
      for (int dd = 0; dd < 8; ++dd) { float df = v[dd] - mur[dd]; t = fmaf(df*df, isgr[dd], t); }
      t += __shfl_xor(t, 32, 64);
      float logit = lar - 0.5f * (t + lsr);
      float mx = logit;
      mx = fmaxf(mx, __shfl_xor(mx, 16, 64));
      mx = fmaxf(mx, __shfl_xor(mx,  8, 64));
      mx = fmaxf(mx, __shfl_xor(mx,  4, 64));
      mx = fmaxf(mx, __shfl_xor(mx,  2, 64));
      mx = fmaxf(mx, __shfl_xor(mx,  1, 64));
      float e = expf(logit - mx);
      float se = e;
      se += __shfl_xor(se, 16, 64);
      se += __shfl_xor(se,  8, 64);
      se += __shfl_xor(se,  4, 64);
      se += __shfl_xor(se,  2, 64);
      se += __shfl_xor(se,  1, 64);
      R = e / se;
    }
    float Ra = R * can;
    rsr += Ra;
    #pragma unroll
    for (int dd = 0; dd < 8; ++dd) {
      s1r[dd] = fmaf(Ra, v[dd], s1r[dd]);
      s2r[dd] = fmaf(Ra * v[dd], v[dd], s2r[dd]);
    }
  }

  #pragma unroll
  for (int dd = 0; dd < 8; ++dd) {
    s1s[wv][o*17 + half*8 + dd] = s1r[dd];
    s2s[wv][o*17 + half*8 + dd] = s2r[dd];
  }
  if (!half) rsP[wv][o] = rsr;
  __syncthreads();

  float* out = stat + (size_t)(bb*12 + chunk) * 1056;
  for (int idx = tid; idx < 512; idx += 256) {
    int oo = idx >> 4, d = idx & 15;
    float S1 = 0.f, S2 = 0.f;
    #pragma unroll
    for (int w2 = 0; w2 < 4; ++w2) { S1 += s1s[w2][oo*17+d]; S2 += s2s[w2][oo*17+d]; }
    out[idx] = S1; out[512 + idx] = S2;
  }
  if (tid < 32) {
    float r = 0.f;
    #pragma unroll
    for (int w2 = 0; w2 < 4; ++w2) r += rsP[w2][tid];
    out[1024 + tid] = r;
  }
}

template<int P>
__global__ __launch_bounds__(256) void dense_comb(
    const float* __restrict__ stat,
    const float* __restrict__ ba, const float* __restrict__ bu,
    float* __restrict__ comb, float* __restrict__ decin)
{
  __shared__ float S0S[32], RsS[32], lgS[32*17];
  const int tid = threadIdx.x;
  const int bb = blockIdx.x;
  const float* st = stat + (size_t)bb * 12 * 1056;
  float* cb = comb + (size_t)bb * 1088;

  if (tid < 32) {
    float r = 0.f;
    #pragma unroll
    for (int c = 0; c < 12; ++c) r += st[c*1056 + 1024 + tid];
    S0S[tid] = r; RsS[tid] = r + EPSR;
  }
  __syncthreads();
  for (int idx = tid; idx < 512; idx += 256) {
    int oo = idx >> 4, d = idx & 15;
    float S1 = 0.f, S2 = 0.f;
    #pragma unroll
    for (int c = 0; c < 12; ++c) { S1 += st[c*1056 + idx]; S2 += st[c*1056 + 512 + idx]; }
    float Rs = RsS[oo];
    float m_ = S1 / Rs;
    float sg = (S2 - 2.f*m_*S1 + m_*m_*S0S[oo]) / Rs + EPSR;
    if (P == 2) {
      decin[(size_t)bb*512 + idx] = m_;
    } else {
      cb[idx] = m_;
      cb[512 + idx] = 1.f / sg;
    }
    lgS[oo*17 + d] = logf(sg);
  }
  __syncthreads();
  if (P < 2 && tid < 32) {
    float L = 0.f;
    #pragma unroll
    for (int d = 0; d < 16; ++d) L += lgS[tid*17 + d];
    float lam = 0.01f * (float)(P + 1);
    float cost = (16.f*bu[tid] + 0.5f*L) * RsS[tid];
    float av = 1.f / (1.f + expf(-lam * (ba[tid] - cost)));
    cb[1024 + tid] = logf(av + EPSR);
    cb[1056 + tid] = 16.f*LOG2PI + L;
  }
}

// ---------------- decoder FC: K-split partial + reduce ----------------
__global__ __launch_bounds__(256) void fc_partial(
    const float* __restrict__ in, const float* __restrict__ W,
    float* __restrict__ part, int K, int N, int CK)
{
  int t = blockIdx.x * 256 + threadIdx.x;
  int nj = N >> 2;
  int j4 = t % nj, ks = t / nj;
  int k0 = ks * CK;
  float4 a0 = make_float4(0,0,0,0), a1 = make_float4(0,0,0,0);
  const float4* Wp = (const float4*)W;
  for (int kk = 0; kk < CK; ++kk) {
    int k = k0 + kk;
    float4 wv = Wp[(size_t)k * nj + j4];
    float f0 = in[k], f1 = in[K + k];
    a0.x = fmaf(f0, wv.x, a0.x); a0.y = fmaf(f0, wv.y, a0.y);
    a0.z = fmaf(f0, wv.z, a0.z); a0.w = fmaf(f0, wv.w, a0.w);
    a1.x = fmaf(f1, wv.x, a1.x); a1.y = fmaf(f1, wv.y, a1.y);
    a1.z = fmaf(f1, wv.z, a1.z); a1.w = fmaf(f1, wv.w, a1.w);
  }
  ((float4*)part)[(size_t)(ks*2 + 0) * nj + j4] = a0;
  ((float4*)part)[(size_t)(ks*2 + 1) * nj + j4] = a1;
}

__global__ __launch_bounds__(256) void fc_reduce(
    const float* __restrict__ part, const float* __restrict__ bias,
    float* __restrict__ out, int N, int KS, int relu)
{
  int t = blockIdx.x * 256 + threadIdx.x;
  int b = t / N, j = t - b*N;
  float s = bias[j];
  for (int ks = 0; ks < KS; ++ks) s += part[(size_t)(ks*2 + b) * N + j];
  if (relu) s = fmaxf(s, 0.f);
  out[(size_t)b*N + j] = s;
}

// ---------------- launch ----------------
extern "C" void kernel_launch(void* const* d_in, const int* in_sizes, int n_in,
                              void* d_out, int out_size, void* d_ws, size_t ws_size,
                              hipStream_t stream) {
  const float* x    = (const float*)d_in[0];
  const float* c1w  = (const float*)d_in[1];
  const float* c1b  = (const float*)d_in[2];
  const float* bn1  = (const float*)d_in[3];
  const float* ppw  = (const float*)d_in[4];
  const float* ppb  = (const float*)d_in[5];
  const float* paw  = (const float*)d_in[6];
  const float* pab  = (const float*)d_in[7];
  const float* bn2  = (const float*)d_in[8];
  const float* ccw1 = (const float*)d_in[9];
  const float* cba1 = (const float*)d_in[10];
  const float* cbu1 = (const float*)d_in[11];
  const float* bn3  = (const float*)d_in[12];
  const float* ccw2 = (const float*)d_in[13];
  const float* cba2 = (const float*)d_in[14];
  const float* cbu2 = (const float*)d_in[15];
  const float* bn4  = (const float*)d_in[16];
  const float* dcw  = (const float*)d_in[17];
  const float* dcba = (const float*)d_in[18];
  const float* dcbu = (const float*)d_in[19];
  const float* w1   = (const float*)d_in[20];
  const float* b1   = (const float*)d_in[21];
  const float* w2   = (const float*)d_in[22];
  const float* b2   = (const float*)d_in[23];
  const float* w3   = (const float*)d_in[24];
  const float* b3   = (const float*)d_in[25];

  float* ws    = (float*)d_ws;
  float* h     = ws + O_H;
  f16*   hh    = (f16*)(ws + O_H);
  f16*   hl    = hh + 786432;
  float* pose2 = ws + O_POSE2;
  float* act2  = ws + O_ACT2;
  float* pose3 = ws + O_POSE3;
  float* act3  = ws + O_ACT3;
  float* pose4 = ws + O_POSE4;
  float* act4  = ws + O_ACT4;
  float* decin = ws + O_DECIN;
  float* h1    = ws + O_H1;
  float* h2    = ws + O_H2;
  float* part  = ws + O_PART;
  f16*   bwh   = (f16*)(ws + O_BWH);
  f16*   bwl   = (f16*)(ws + O_BWL);
  float* dstat = ws + O_DSTAT;
  float* dcomb = ws + O_DCOMB;

  const bool fast = ws_size >= NEED_BYTES;

  if (fast) {
    conv1_k<1><<<3072, 256, 0, stream>>>(x, c1w, c1b, bn1, nullptr, hh, hl);
    split_w_k<<<dim3(243, 20), 256, 0, stream>>>(ppw, paw, bwh, bwl);
    zero_raw<<<3332, 256, 0, stream>>>(pose2, act2);
    conv2_mfma<<<dim3(13, 5, 8), 256, 0, stream>>>(hh, hl, bwh, bwl, pose2, act2);
  } else {
    conv1_k<0><<<3072, 256, 0, stream>>>(x, c1w, c1b, bn1, h, nullptr, nullptr);
    zero_raw<<<3332, 256, 0, stream>>>(pose2, act2);
    conv2_gemm_ks<<<dim3(25, 9, 6), 256, 0, stream>>>(h, ppw, paw, pose2, act2);
  }
  conv2_epi<<<3332, 256, 0, stream>>>(ppb, pab, bn2, pose2, act2);
  routing_k<288, 16, true><<<338, 1024, 0, stream>>>(pose2, act2, ccw1, cba1, cbu1, bn3,
                                                     pose3, act3, 28, 28, 13);
  routing_k<288, 16, true><<<72, 1024, 0, stream>>>(pose3, act3, ccw2, cba2, cbu2, bn4,
                                                    pose4, act4, 13, 13, 6);
  dense_stats<0><<<24, 256, 0, stream>>>(pose4, act4, dcw, nullptr, dstat);
  dense_comb<0><<<2, 256, 0, stream>>>(dstat, dcba, dcbu, dcomb, nullptr);
  dense_stats<1><<<24, 256, 0, stream>>>(pose4, act4, dcw, dcomb, dstat);
  dense_comb<1><<<2, 256, 0, stream>>>(dstat, dcba, dcbu, dcomb, nullptr);
  dense_stats<2><<<24, 256, 0, stream>>>(pose4, act4, dcw, dcomb, dstat);
  dense_comb<2><<<2, 256, 0, stream>>>(dstat, dcba, dcbu, dcomb, decin);
  fc_partial<<<16, 256, 0, stream>>>(decin, w1, part, 512, 512, 16);
  fc_reduce<<<4, 256, 0, stream>>>(part, b1, h1, 512, 32, 1);
  fc_partial<<<32, 256, 0, stream>>>(h1, w2, part, 512, 1024, 16);
  fc_reduce<<<8, 256, 0, stream>>>(part, b2, h2, 1024, 32, 1);
  fc_partial<<<256, 256, 0, stream>>>(h2, w3, part, 1024, 8192, 32);
  fc_reduce<<<64, 256, 0, stream>>>(part, b3, (float*)d_out, 8192, 32, 0);
}